// Round 4
// baseline (874.856 us; speedup 1.0000x reference)
//
#include <hip/hip_runtime.h>
#include <stdint.h>
#include <stddef.h>

// ---------------------------------------------------------------------------
// Fully fake-quantized transformer block on MI355X (gfx950).
// All GEMMs run as int8 MFMA (v_mfma_i32_16x16x64_i8), exact i32 accumulation,
// dequant in f32 epilogues. Attention fused flash-style (softmax global max
// == 1.0 exactly => s_attn = 1/127 static).
// Inputs: float32 (proven round 3: dtype-probe flag flipped behavior).
// OUTPUT: float32 (reference returns f32; round-3 failure was bf16 packing).
// Workspace peak: 52.07 MB.
// ---------------------------------------------------------------------------

typedef unsigned short u16;
typedef __attribute__((ext_vector_type(4))) int   i32x4;
typedef __attribute__((ext_vector_type(4))) float f32x4;

#define DEV __device__ __forceinline__

DEV float bf2f(u16 u) { return __uint_as_float(((unsigned)u) << 16); }
DEV void atomicMaxF(float* p, float v) { atomicMax((unsigned*)p, __float_as_uint(v)); }
DEV float waveMax(float v) {
#pragma unroll
  for (int o = 32; o; o >>= 1) v = fmaxf(v, __shfl_xor(v, o, 64));
  return v;
}
DEV float waveSum(float v) {
#pragma unroll
  for (int o = 32; o; o >>= 1) v += __shfl_xor(v, o, 64);
  return v;
}
DEV int waveSumI(int v) {
#pragma unroll
  for (int o = 32; o; o >>= 1) v += __shfl_xor(v, o, 64);
  return v;
}
// load 4 consecutive input elements (group index i4) as f32, either dtype
DEV f32x4 ld4(const void* p, int i4, int isf32) {
  if (isf32) return ((const f32x4*)p)[i4];
  ushort4 u = ((const ushort4*)p)[i4];
  return (f32x4){bf2f(u.x), bf2f(u.y), bf2f(u.z), bf2f(u.w)};
}
// async global->LDS, 16B/lane; wave-uniform base + lane*16 (m97 pattern)
DEV void gll16(const void* g, void* l) {
  __builtin_amdgcn_global_load_lds((__attribute__((address_space(1))) void*)(g),
                                   (__attribute__((address_space(3))) void*)(l),
                                   16, 0, 0);
}

// --------------------------- input dtype probe -------------------------------
// f32 N(0,1): low 16-bit halves ~uniform => as bf16, ~47% have |v|>=256
// (bits (u&0x7f80)>=0x4380). bf16 N(0,1): never.
__global__ void detect_f32(const u16* __restrict__ x, int* __restrict__ flag) {
  const int tid = threadIdx.x;  // 64 threads
  int cnt = 0;
#pragma unroll
  for (int i = 0; i < 16; ++i) {
    u16 u = x[tid * 16 + i];
    if ((u & 0x7f80u) >= 0x4380u) ++cnt;
  }
  cnt = waveSumI(cnt);
  if (tid == 0) flag[0] = (cnt > 16) ? 1 : 0;
}

// --------------------------- reductions over inputs -------------------------
struct AJobs { const void* p[13]; int n4[13]; int bstart[14]; };

__global__ __launch_bounds__(256) void absmax_multi(AJobs J, float* __restrict__ M,
                                                    const int* __restrict__ flagp) {
  const int isf32 = flagp[0];
  const int blk = blockIdx.x, tid = threadIdx.x;
  int j = 0;
  while (j < 12 && blk >= J.bstart[j + 1]) ++j;
  const int lb = blk - J.bstart[j];
  const int nb = J.bstart[j + 1] - J.bstart[j];
  float mx = 0.f;
  const void* p = J.p[j];
  for (int i = lb * 256 + tid; i < J.n4[j]; i += nb * 256) {
    f32x4 v = ld4(p, i, isf32);
    mx = fmaxf(mx, fmaxf(fmaxf(fabsf(v.x), fabsf(v.y)),
                         fmaxf(fabsf(v.z), fabsf(v.w))));
  }
  mx = waveMax(mx);
  if ((tid & 63) == 0) atomicMaxF(&M[j], mx);
}

// --------------------------- quantizers -------------------------------------
__global__ __launch_bounds__(256) void quant_in_signed(
    const void* __restrict__ in, int8_t* __restrict__ out,
    const float* __restrict__ mp, const int* __restrict__ flagp, int n4) {
  const int isf32 = flagp[0];
  const float s = fmaxf(mp[0], 1e-8f) / 127.0f;
  char4* op = (char4*)out;
  for (int i = blockIdx.x * 256 + threadIdx.x; i < n4; i += gridDim.x * 256) {
    f32x4 v = ld4(in, i, isf32);
    char4 q;
    q.x = (signed char)fminf(fmaxf(rintf(v.x / s), -128.f), 127.f);
    q.y = (signed char)fminf(fmaxf(rintf(v.y / s), -128.f), 127.f);
    q.z = (signed char)fminf(fmaxf(rintf(v.z / s), -128.f), 127.f);
    q.w = (signed char)fminf(fmaxf(rintf(v.w / s), -128.f), 127.f);
    op[i] = q;
  }
}

struct WJobs { const void* in[5]; int8_t* out[5]; int mslot[5]; int n4[5]; int bstart[6]; };

__global__ __launch_bounds__(256) void quant_w_multi(WJobs J, const float* __restrict__ M,
                                                     const int* __restrict__ flagp) {
  const int isf32 = flagp[0];
  const int blk = blockIdx.x, tid = threadIdx.x;
  int j = 0;
  while (j < 4 && blk >= J.bstart[j + 1]) ++j;
  const int lb = blk - J.bstart[j];
  const int nb = J.bstart[j + 1] - J.bstart[j];
  const float s = fmaxf(M[J.mslot[j]], 1e-8f) / 127.0f;
  const void* p = J.in[j];
  char4* o = (char4*)J.out[j];
  for (int i = lb * 256 + tid; i < J.n4[j]; i += nb * 256) {
    f32x4 v = ld4(p, i, isf32);
    char4 q;
    q.x = (signed char)fminf(fmaxf(rintf(v.x / s), -127.f), 127.f);
    q.y = (signed char)fminf(fmaxf(rintf(v.y / s), -127.f), 127.f);
    q.z = (signed char)fminf(fmaxf(rintf(v.z / s), -127.f), 127.f);
    q.w = (signed char)fminf(fmaxf(rintf(v.w / s), -127.f), 127.f);
    o[i] = q;
  }
}

// W2 (1024 x 4096) narrow quant + per-row int sum (u8 offset trick)
__global__ __launch_bounds__(256) void quant_w2_rs(
    const void* __restrict__ w2, int8_t* __restrict__ out,
    const float* __restrict__ mp, const int* __restrict__ flagp,
    int* __restrict__ rowsum) {
  const int isf32 = flagp[0];
  const int row = blockIdx.x, tid = threadIdx.x;
  const float s = fmaxf(mp[0], 1e-8f) / 127.0f;
  char4* op = (char4*)(out + (size_t)row * 4096);
  int sum = 0;
  for (int i = tid; i < 1024; i += 256) {
    f32x4 v = ld4(w2, row * 1024 + i, isf32);
    char4 q;
    q.x = (signed char)fminf(fmaxf(rintf(v.x / s), -127.f), 127.f);
    q.y = (signed char)fminf(fmaxf(rintf(v.y / s), -127.f), 127.f);
    q.z = (signed char)fminf(fmaxf(rintf(v.z / s), -127.f), 127.f);
    q.w = (signed char)fminf(fmaxf(rintf(v.w / s), -127.f), 127.f);
    op[i] = q;
    sum += (int)q.x + (int)q.y + (int)q.z + (int)q.w;
  }
  sum = waveSumI(sum);
  __shared__ int rs4[4];
  if ((tid & 63) == 0) rs4[tid >> 6] = sum;
  __syncthreads();
  if (tid == 0) rowsum[row] = rs4[0] + rs4[1] + rs4[2] + rs4[3];
}

struct BJobs { const void* in[6]; float* out[6]; int mslot[6]; int n4[6]; };

__global__ __launch_bounds__(256) void fq_bias_multi(BJobs J, const float* __restrict__ M,
                                                     const int* __restrict__ flagp) {
  const int isf32 = flagp[0];
  const int j = blockIdx.x;
  const float s = fmaxf(M[J.mslot[j]], 1e-8f) / 127.0f;
  float* o = J.out[j];
  for (int i = threadIdx.x; i < J.n4[j]; i += 256) {
    f32x4 v = ld4(J.in[j], i, isf32);
    f32x4 r;
    r.x = fminf(fmaxf(rintf(v.x / s), -128.f), 127.f) * s;
    r.y = fminf(fmaxf(rintf(v.y / s), -128.f), 127.f) * s;
    r.z = fminf(fmaxf(rintf(v.z / s), -128.f), 127.f) * s;
    r.w = fminf(fmaxf(rintf(v.w / s), -128.f), 127.f) * s;
    *(f32x4*)(o + i * 4) = r;
  }
}

// f32 -> i8 signed (pre scales both value and stat; pre=0.125 for Q/sqrt(D))
__global__ __launch_bounds__(256) void quant_f32_signed(
    const float* __restrict__ in, int8_t* __restrict__ out,
    const float* __restrict__ mp, float pre, int n4) {
  const float s = fmaxf(mp[0] * pre, 1e-8f) / 127.0f;
  const f32x4* ip = (const f32x4*)in;
  char4* op = (char4*)out;
  for (int i = blockIdx.x * 256 + threadIdx.x; i < n4; i += gridDim.x * 256) {
    f32x4 v = ip[i];
    char4 q;
    q.x = (signed char)fminf(fmaxf(rintf(v.x * pre / s), -128.f), 127.f);
    q.y = (signed char)fminf(fmaxf(rintf(v.y * pre / s), -128.f), 127.f);
    q.z = (signed char)fminf(fmaxf(rintf(v.z * pre / s), -128.f), 127.f);
    q.w = (signed char)fminf(fmaxf(rintf(v.w * pre / s), -128.f), 127.f);
    op[i] = q;
  }
}

// V (f32 [b,s,h,d]) -> i8 transposed [b,h,d,s] so PV B-frags are k-contiguous
__global__ __launch_bounds__(256) void quant_v_t(
    const float* __restrict__ V, int8_t* __restrict__ Vt,
    const float* __restrict__ mp) {
  __shared__ float tile[64][65];
  const int bh = blockIdx.x, st = blockIdx.y;
  const int b = bh >> 4, h = bh & 15;
  const int tid = threadIdx.x;
  const float s = fmaxf(mp[0], 1e-8f) / 127.0f;
  const int r = tid >> 2, c = (tid & 3) * 16;
  const float* src = V + ((size_t)(b * 1024 + st * 64 + r)) * 1024 + h * 64 + c;
#pragma unroll
  for (int g = 0; g < 4; ++g) {
    f32x4 v = *(const f32x4*)(src + g * 4);
    tile[r][c + g * 4 + 0] = v.x;
    tile[r][c + g * 4 + 1] = v.y;
    tile[r][c + g * 4 + 2] = v.z;
    tile[r][c + g * 4 + 3] = v.w;
  }
  __syncthreads();
  unsigned wds[4];
#pragma unroll
  for (int g = 0; g < 4; ++g) {
    unsigned wd = 0;
#pragma unroll
    for (int k = 0; k < 4; ++k) {
      float v = tile[c + g * 4 + k][r];
      int q = (int)fminf(fmaxf(rintf(v / s), -128.f), 127.f);
      wd |= ((unsigned)(unsigned char)(signed char)q) << (8 * k);
    }
    wds[g] = wd;
  }
  i32x4 ov = {(int)wds[0], (int)wds[1], (int)wds[2], (int)wds[3]};
  *(i32x4*)(Vt + ((size_t)((b * 16 + h) * 64 + r)) * 1024 + st * 64 + c) = ov;
}

// --------------------------- int8 GEMM (m97-style) ---------------------------
// acc = Σk A[n,k]B[o,k] (exact i32); v = sA*sB*(acc + ext[o]) + bias[o]; relu?
// mode 0: store f32 Cf, absmax->mOut
// mode 1: stats only (absmax of v -> mOut), no store   [MLP1 pass 1]
// mode 2: read stat mOut, store clip(round(v/s),0,255)-128 as i8 Cq  [pass 2]
__global__ __launch_bounds__(256) void gemm_i8(
    const int8_t* __restrict__ A, const int8_t* __restrict__ B,
    float* __restrict__ Cf, int8_t* __restrict__ Cq,
    const float* __restrict__ mA, float preA, float qmaxA,
    const float* __restrict__ mB,
    const float* __restrict__ bias, const int* __restrict__ extra,
    int relu, int mode, float* __restrict__ mOut, int K, int O) {
  __shared__ __align__(16) int8_t At[8192];
  __shared__ __align__(16) int8_t Bt[8192];
  const int tid = threadIdx.x;
  const int nb = blockIdx.x, ob = blockIdx.y;
  const int w = tid >> 6, lane = tid & 63, l15 = lane & 15, quad = lane >> 4;
  const int wr = w >> 1, wc = w & 1;
  i32x4 acc[4][4];
#pragma unroll
  for (int i = 0; i < 4; ++i)
#pragma unroll
    for (int j = 0; j < 4; ++j) acc[i][j] = (i32x4){0, 0, 0, 0};
  const int r0 = tid >> 2, c0 = (tid & 3) * 16;
  const int8_t* Ab = A + (size_t)(nb * 128) * K;
  const int8_t* Bb = B + (size_t)(ob * 128) * K;
  for (int kt = 0; kt < K; kt += 64) {
    gll16(Ab + (size_t)r0 * K + kt + c0, At + tid * 16);
    gll16(Ab + (size_t)(r0 + 64) * K + kt + c0, At + 4096 + tid * 16);
    gll16(Bb + (size_t)r0 * K + kt + c0, Bt + tid * 16);
    gll16(Bb + (size_t)(r0 + 64) * K + kt + c0, Bt + 4096 + tid * 16);
    __syncthreads();
    i32x4 af[4], bf[4];
#pragma unroll
    for (int mt = 0; mt < 4; ++mt)
      af[mt] = *(const i32x4*)(At + (wr * 64 + mt * 16 + l15) * 64 + quad * 16);
#pragma unroll
    for (int nt = 0; nt < 4; ++nt)
      bf[nt] = *(const i32x4*)(Bt + (wc * 64 + nt * 16 + l15) * 64 + quad * 16);
#pragma unroll
    for (int mt = 0; mt < 4; ++mt)
#pragma unroll
      for (int nt = 0; nt < 4; ++nt)
        acc[mt][nt] = __builtin_amdgcn_mfma_i32_16x16x64_i8(af[mt], bf[nt], acc[mt][nt], 0, 0, 0);
    __syncthreads();
  }
  const float sA = fmaxf(mA[0] * preA, 1e-8f) / qmaxA;
  const float sB = fmaxf(mB[0], 1e-8f) / 127.0f;
  const float sAB = sA * sB;
  const float sq = (mode == 2) ? (fmaxf(mOut[0], 1e-8f) / 255.0f) : 1.0f;
  float lmax = 0.f;
#pragma unroll
  for (int mt = 0; mt < 4; ++mt) {
    const int n = nb * 128 + wr * 64 + mt * 16 + quad * 4;
#pragma unroll
    for (int nt = 0; nt < 4; ++nt) {
      const int o = ob * 128 + wc * 64 + nt * 16 + l15;
      const int ext = extra ? 128 * extra[o] : 0;
      const float bv = bias[o];
#pragma unroll
      for (int r = 0; r < 4; ++r) {
        float v = sAB * (float)(acc[mt][nt][r] + ext) + bv;
        if (relu) v = fmaxf(v, 0.f);
        if (mode == 0) Cf[(size_t)(n + r) * O + o] = v;
        else if (mode == 2) {
          int q = (int)fminf(fmaxf(rintf(v / sq), 0.f), 255.f) - 128;
          Cq[(size_t)(n + r) * O + o] = (int8_t)q;
        }
        lmax = fmaxf(lmax, fabsf(v));
      }
    }
  }
  if (mode != 2) {
    lmax = waveMax(lmax);
    if (lane == 0) atomicMaxF(mOut, lmax);
  }
}

// --------------------------- fused causal attention --------------------------
__global__ __launch_bounds__(256) void attn_fused(
    const int8_t* __restrict__ Qq, const int8_t* __restrict__ Kq,
    const int8_t* __restrict__ Vt, float* __restrict__ ctx,
    const float* __restrict__ M, float* __restrict__ mOut) {
  __shared__ __align__(16) int8_t qtile[4096];
  __shared__ __align__(16) int8_t ktile[4096];
  __shared__ __align__(16) int8_t vtile[4096];
  __shared__ __align__(16) float ptile[4096];
  const int tid = threadIdx.x, bid = blockIdx.x;
  const int qt = bid & 15, h = (bid >> 4) & 15, b = bid >> 8;
  const int w = tid >> 6, lane = tid & 63, l15 = lane & 15, quad = lane >> 4;
  const float sqs = fmaxf(M[13] * 0.125f, 1e-8f) / 127.0f;
  const float sk = fmaxf(M[14], 1e-8f) / 127.0f;
  const float sv = fmaxf(M[15], 1e-8f) / 127.0f;
  const float sqk = sqs * sk;
  const float s_attn = 1.0f / 127.0f;  // softmax global max is exactly 1.0
  const int r0 = tid >> 2, c0 = (tid & 3) * 16;

  gll16(Qq + ((size_t)(b * 1024 + qt * 64 + r0)) * 1024 + h * 64 + c0, qtile + tid * 16);
  __syncthreads();
  const i32x4 aq = *(const i32x4*)(qtile + (w * 16 + l15) * 64 + quad * 16);
  const int qrow0 = qt * 64 + w * 16 + quad * 4;

  float mrow[4] = {-1e30f, -1e30f, -1e30f, -1e30f};
  float lrow[4] = {0.f, 0.f, 0.f, 0.f};

  for (int kt = 0; kt <= qt; ++kt) {
    __syncthreads();
    gll16(Kq + ((size_t)(b * 1024 + kt * 64 + r0)) * 1024 + h * 64 + c0, ktile + tid * 16);
    __syncthreads();
    float sc[4][4];
#pragma unroll
    for (int nt = 0; nt < 4; ++nt) {
      i32x4 z = {0, 0, 0, 0};
      i32x4 bk = *(const i32x4*)(ktile + (nt * 16 + l15) * 64 + quad * 16);
      i32x4 d = __builtin_amdgcn_mfma_i32_16x16x64_i8(aq, bk, z, 0, 0, 0);
      const int kcol = kt * 64 + nt * 16 + l15;
#pragma unroll
      for (int r = 0; r < 4; ++r)
        sc[nt][r] = (kcol <= qrow0 + r) ? sqk * (float)d[r] : -1e30f;
    }
#pragma unroll
    for (int r = 0; r < 4; ++r) {
      float v = fmaxf(fmaxf(sc[0][r], sc[1][r]), fmaxf(sc[2][r], sc[3][r]));
      v = fmaxf(v, __shfl_xor(v, 1, 64));
      v = fmaxf(v, __shfl_xor(v, 2, 64));
      v = fmaxf(v, __shfl_xor(v, 4, 64));
      v = fmaxf(v, __shfl_xor(v, 8, 64));
      const float mn = fmaxf(mrow[r], v);
      float ps = expf(sc[0][r] - mn) + expf(sc[1][r] - mn) +
                 expf(sc[2][r] - mn) + expf(sc[3][r] - mn);
      ps += __shfl_xor(ps, 1, 64);
      ps += __shfl_xor(ps, 2, 64);
      ps += __shfl_xor(ps, 4, 64);
      ps += __shfl_xor(ps, 8, 64);
      lrow[r] = lrow[r] * expf(mrow[r] - mn) + ps;
      mrow[r] = mn;
    }
  }

  i32x4 cacc[4] = {{0, 0, 0, 0}, {0, 0, 0, 0}, {0, 0, 0, 0}, {0, 0, 0, 0}};
  for (int kt = 0; kt <= qt; ++kt) {
    __syncthreads();
    gll16(Kq + ((size_t)(b * 1024 + kt * 64 + r0)) * 1024 + h * 64 + c0, ktile + tid * 16);
    gll16(Vt + ((size_t)((b * 16 + h) * 64 + r0)) * 1024 + kt * 64 + c0, vtile + tid * 16);
    __syncthreads();
#pragma unroll
    for (int nt = 0; nt < 4; ++nt) {
      i32x4 z = {0, 0, 0, 0};
      i32x4 bk = *(const i32x4*)(ktile + (nt * 16 + l15) * 64 + quad * 16);
      i32x4 d = __builtin_amdgcn_mfma_i32_16x16x64_i8(aq, bk, z, 0, 0, 0);
      const int kcol = kt * 64 + nt * 16 + l15;
#pragma unroll
      for (int r = 0; r < 4; ++r) {
        float e = 0.f;
        if (kcol <= qrow0 + r)
          e = expf(sqk * (float)d[r] - mrow[r]) / lrow[r];
        ptile[(w * 16 + quad * 4 + r) * 64 + nt * 16 + l15] = e;
      }
    }
    __syncthreads();
    const float* pr = ptile + (w * 16 + l15) * 64 + quad * 16;
    unsigned pb[4];
#pragma unroll
    for (int g = 0; g < 4; ++g) {
      f32x4 pv = *(const f32x4*)(pr + g * 4);
      unsigned b0 = (unsigned)(int)fminf(fmaxf(rintf(pv.x * 127.0f), 0.f), 127.f);
      unsigned b1 = (unsigned)(int)fminf(fmaxf(rintf(pv.y * 127.0f), 0.f), 127.f);
      unsigned b2 = (unsigned)(int)fminf(fmaxf(rintf(pv.z * 127.0f), 0.f), 127.f);
      unsigned b3 = (unsigned)(int)fminf(fmaxf(rintf(pv.w * 127.0f), 0.f), 127.f);
      pb[g] = b0 | (b1 << 8) | (b2 << 16) | (b3 << 24);
    }
    i32x4 pf = {(int)pb[0], (int)pb[1], (int)pb[2], (int)pb[3]};
#pragma unroll
    for (int nt = 0; nt < 4; ++nt) {
      i32x4 bv = *(const i32x4*)(vtile + (nt * 16 + l15) * 64 + quad * 16);
      cacc[nt] = __builtin_amdgcn_mfma_i32_16x16x64_i8(pf, bv, cacc[nt], 0, 0, 0);
    }
  }
  const float sc2 = s_attn * sv;
  float lmax = 0.f;
#pragma unroll
  for (int nt = 0; nt < 4; ++nt) {
    const int d = nt * 16 + l15;
#pragma unroll
    for (int r = 0; r < 4; ++r) {
      float v = sc2 * (float)cacc[nt][r];
      ctx[((size_t)(b * 1024 + qrow0 + r)) * 1024 + h * 64 + d] = v;
      lmax = fmaxf(lmax, fabsf(v));
    }
  }
  lmax = waveMax(lmax);
  if (lane == 0) atomicMaxF(mOut, lmax);
}

// --------------------------- residual + layernorm ---------------------------
__global__ __launch_bounds__(256) void ln_res(
    const int8_t* __restrict__ xq, const float* __restrict__ mx,
    const float* __restrict__ ao, const float* __restrict__ ma,
    float* __restrict__ x1, float* __restrict__ mOut) {
  const int row = blockIdx.x, tid = threadIdx.x;
  const float sx = fmaxf(mx[0], 1e-8f) / 127.0f;
  const float sa = fmaxf(ma[0], 1e-8f) / 127.0f;
  char4 xv = *(const char4*)(xq + (size_t)row * 1024 + tid * 4);
  f32x4 av = *(const f32x4*)(ao + (size_t)row * 1024 + tid * 4);
  float t[4];
  t[0] = (float)xv.x * sx + fminf(fmaxf(rintf(av.x / sa), -128.f), 127.f) * sa;
  t[1] = (float)xv.y * sx + fminf(fmaxf(rintf(av.y / sa), -128.f), 127.f) * sa;
  t[2] = (float)xv.z * sx + fminf(fmaxf(rintf(av.z / sa), -128.f), 127.f) * sa;
  t[3] = (float)xv.w * sx + fminf(fmaxf(rintf(av.w / sa), -128.f), 127.f) * sa;
  __shared__ float red[8];
  float s = waveSum(t[0] + t[1] + t[2] + t[3]);
  if ((tid & 63) == 0) red[tid >> 6] = s;
  __syncthreads();
  const float mean = (red[0] + red[1] + red[2] + red[3]) * (1.0f / 1024.0f);
  float vs = 0.f;
#pragma unroll
  for (int i = 0; i < 4; ++i) { float d = t[i] - mean; vs += d * d; }
  vs = waveSum(vs);
  if ((tid & 63) == 0) red[4 + (tid >> 6)] = vs;
  __syncthreads();
  const float var = (red[4] + red[5] + red[6] + red[7]) * (1.0f / 1024.0f);
  const float rs = sqrtf(var + 1e-5f);
  f32x4 o;
  o.x = (t[0] - mean) / rs;
  o.y = (t[1] - mean) / rs;
  o.z = (t[2] - mean) / rs;
  o.w = (t[3] - mean) / rs;
  *(f32x4*)(x1 + (size_t)row * 1024 + tid * 4) = o;
  float lmax = fmaxf(fmaxf(fabsf(o.x), fabsf(o.y)), fmaxf(fabsf(o.z), fabsf(o.w)));
  lmax = waveMax(lmax);
  if ((tid & 63) == 0) atomicMaxF(mOut, lmax);
}

// final residual + layernorm; OUTPUT IS FLOAT32 (reference returns f32)
__global__ __launch_bounds__(256) void ln_final(
    const int8_t* __restrict__ x1q, const float* __restrict__ mx1,
    const float* __restrict__ h2, const float* __restrict__ mh2,
    float* __restrict__ out) {
  const int row = blockIdx.x, tid = threadIdx.x;
  const float s1 = fmaxf(mx1[0], 1e-8f) / 127.0f;
  const float s2 = fmaxf(mh2[0], 1e-8f) / 127.0f;
  char4 xv = *(const char4*)(x1q + (size_t)row * 1024 + tid * 4);
  f32x4 hv = *(const f32x4*)(h2 + (size_t)row * 1024 + tid * 4);
  float t[4];
  t[0] = (float)xv.x * s1 + fminf(fmaxf(rintf(hv.x / s2), -128.f), 127.f) * s2;
  t[1] = (float)xv.y * s1 + fminf(fmaxf(rintf(hv.y / s2), -128.f), 127.f) * s2;
  t[2] = (float)xv.z * s1 + fminf(fmaxf(rintf(hv.z / s2), -128.f), 127.f) * s2;
  t[3] = (float)xv.w * s1 + fminf(fmaxf(rintf(hv.w / s2), -128.f), 127.f) * s2;
  __shared__ float red[8];
  float s = waveSum(t[0] + t[1] + t[2] + t[3]);
  if ((tid & 63) == 0) red[tid >> 6] = s;
  __syncthreads();
  const float mean = (red[0] + red[1] + red[2] + red[3]) * (1.0f / 1024.0f);
  float vs = 0.f;
#pragma unroll
  for (int i = 0; i < 4; ++i) { float d = t[i] - mean; vs += d * d; }
  vs = waveSum(vs);
  if ((tid & 63) == 0) red[4 + (tid >> 6)] = vs;
  __syncthreads();
  const float var = (red[4] + red[5] + red[6] + red[7]) * (1.0f / 1024.0f);
  const float rs = sqrtf(var + 1e-5f);
  f32x4 o;
  o.x = (t[0] - mean) / rs;
  o.y = (t[1] - mean) / rs;
  o.z = (t[2] - mean) / rs;
  o.w = (t[3] - mean) / rs;
  *(f32x4*)(out + (size_t)row * 1024 + tid * 4) = o;
}

// --------------------------- workspace layout (52.07 MB peak) ----------------
static constexpr size_t MB = 1u << 20;
static constexpr size_t OFF_M     = 0;                    // 64 f32 slots (flag at [32])
static constexpr size_t OFF_BIASQ = 256;
static constexpr size_t OFF_BIASK = OFF_BIASQ + 4096;
static constexpr size_t OFF_BIASV = OFF_BIASK + 4096;
static constexpr size_t OFF_BIASO = OFF_BIASV + 4096;
static constexpr size_t OFF_BIAS1 = OFF_BIASO + 4096;     // 4096 f32
static constexpr size_t OFF_BIAS2 = OFF_BIAS1 + 16384;
static constexpr size_t OFF_RS    = OFF_BIAS2 + 4096;     // 1024 i32
static constexpr size_t OFF_XQ    = 65536;                // 4 MB
static constexpr size_t OFF_WQQ   = OFF_XQ  + 4 * MB;     // 1 MB
static constexpr size_t OFF_WKQ   = OFF_WQQ + 1 * MB;
static constexpr size_t OFF_WVQ   = OFF_WKQ + 1 * MB;
static constexpr size_t OFF_WOQ   = OFF_WVQ + 1 * MB;
static constexpr size_t OFF_W1Q   = OFF_WOQ + 1 * MB;     // 4 MB
static constexpr size_t OFF_W2Q   = OFF_W1Q + 4 * MB;     // 4 MB
static constexpr size_t OFF_X1Q   = OFF_W2Q + 4 * MB;     // 4 MB
static constexpr size_t OFF_A1    = OFF_X1Q + 4 * MB;     // arena1, 16 MB
static constexpr size_t OFF_A2    = OFF_A1 + 16 * MB;     // arena2 (f32), 16 MB
// total = OFF_A2 + 16 MB = 52.06 MB

extern "C" void kernel_launch(void* const* d_in, const int* in_sizes, int n_in,
                              void* d_out, int out_size, void* d_ws, size_t ws_size,
                              hipStream_t stream) {
  (void)n_in; (void)out_size; (void)ws_size;
  char* ws = (char*)d_ws;
  float* M = (float*)(ws + OFF_M);
  int* FLAG = (int*)(M + 32);
  float* BIASQ = (float*)(ws + OFF_BIASQ);
  float* BIASK = (float*)(ws + OFF_BIASK);
  float* BIASV = (float*)(ws + OFF_BIASV);
  float* BIASO = (float*)(ws + OFF_BIASO);
  float* BIAS1 = (float*)(ws + OFF_BIAS1);
  float* BIAS2 = (float*)(ws + OFF_BIAS2);
  int* RS = (int*)(ws + OFF_RS);
  int8_t* XQ  = (int8_t*)(ws + OFF_XQ);
  int8_t* WQQ = (int8_t*)(ws + OFF_WQQ);
  int8_t* WKQ = (int8_t*)(ws + OFF_WKQ);
  int8_t* WVQ = (int8_t*)(ws + OFF_WVQ);
  int8_t* WOQ = (int8_t*)(ws + OFF_WOQ);
  int8_t* W1Q = (int8_t*)(ws + OFF_W1Q);
  int8_t* W2Q = (int8_t*)(ws + OFF_W2Q);
  int8_t* X1Q = (int8_t*)(ws + OFF_X1Q);
  // arena1 (16 MB): QQ/KQ/VT/CTXQ during attention+out-proj; then X1F; then HQ
  int8_t* QQ   = (int8_t*)(ws + OFF_A1);
  int8_t* KQQ  = (int8_t*)(ws + OFF_A1 + 4 * MB);
  int8_t* VT   = (int8_t*)(ws + OFF_A1 + 8 * MB);
  int8_t* CTXQ = (int8_t*)(ws + OFF_A1 + 12 * MB);
  float*  X1F  = (float*)(ws + OFF_A1);     // after out-proj, arena1 i8 all dead
  int8_t* HQ   = (int8_t*)(ws + OFF_A1);    // after X1Q extracted, X1F dead
  // arena2 (16 MB f32): strictly serial reuse on the stream
  float* FBUF = (float*)(ws + OFF_A2);       // QF / KF / VF / CTXF / AOF / H2F

  hipMemsetAsync(M, 0, 256, stream);
  detect_f32<<<1, 64, 0, stream>>>((const u16*)d_in[0], FLAG);

  // input absmax reductions (slot i = max|d_in[i]|)
  AJobs aj;
  const int ablk[13] = {512, 128, 1, 128, 1, 128, 1, 128, 1, 512, 2, 512, 1};
  int bs = 0;
  for (int i = 0; i < 13; ++i) {
    aj.p[i] = d_in[i];
    aj.n4[i] = in_sizes[i] / 4;
    aj.bstart[i] = bs;
    bs += ablk[i];
  }
  aj.bstart[13] = bs;
  absmax_multi<<<bs, 256, 0, stream>>>(aj, M, FLAG);

  quant_in_signed<<<1024, 256, 0, stream>>>(d_in[0], XQ, M + 0, FLAG, in_sizes[0] / 4);

  WJobs wj;
  const int widx[5] = {1, 3, 5, 7, 9};
  int8_t* wout[5] = {WQQ, WKQ, WVQ, WOQ, W1Q};
  const int wblk[5] = {128, 128, 128, 128, 512};
  int wb = 0;
  for (int j = 0; j < 5; ++j) {
    wj.in[j] = d_in[widx[j]];
    wj.out[j] = wout[j];
    wj.mslot[j] = widx[j];
    wj.n4[j] = in_sizes[widx[j]] / 4;
    wj.bstart[j] = wb;
    wb += wblk[j];
  }
  wj.bstart[5] = wb;
  quant_w_multi<<<wb, 256, 0, stream>>>(wj, M, FLAG);
  quant_w2_rs<<<1024, 256, 0, stream>>>(d_in[11], W2Q, M + 11, FLAG, RS);

  BJobs bj;
  const int bidx[6] = {2, 4, 6, 8, 10, 12};
  float* bout[6] = {BIASQ, BIASK, BIASV, BIASO, BIAS1, BIAS2};
  for (int j = 0; j < 6; ++j) {
    bj.in[j] = d_in[bidx[j]];
    bj.out[j] = bout[j];
    bj.mslot[j] = bidx[j];
    bj.n4[j] = in_sizes[bidx[j]] / 4;
  }
  fq_bias_multi<<<6, 256, 0, stream>>>(bj, M, FLAG);

  // Q proj -> FBUF -> QQ
  gemm_i8<<<dim3(32, 8), 256, 0, stream>>>(XQ, WQQ, FBUF, nullptr, M + 0, 1.f, 127.f, M + 1, BIASQ, nullptr, 0, 0, M + 13, 1024, 1024);
  quant_f32_signed<<<2048, 256, 0, stream>>>(FBUF, QQ, M + 13, 0.125f, 1024 * 1024);
  // K proj -> FBUF -> KQ
  gemm_i8<<<dim3(32, 8), 256, 0, stream>>>(XQ, WKQ, FBUF, nullptr, M + 0, 1.f, 127.f, M + 3, BIASK, nullptr, 0, 0, M + 14, 1024, 1024);
  quant_f32_signed<<<2048, 256, 0, stream>>>(FBUF, KQQ, M + 14, 1.0f, 1024 * 1024);
  // V proj -> FBUF -> VT ([b,h,d,s])
  gemm_i8<<<dim3(32, 8), 256, 0, stream>>>(XQ, WVQ, FBUF, nullptr, M + 0, 1.f, 127.f, M + 5, BIASV, nullptr, 0, 0, M + 15, 1024, 1024);
  quant_v_t<<<dim3(64, 16), 256, 0, stream>>>(FBUF, VT, M + 15);

  // fused causal attention -> ctx f32 (FBUF) + max|ctx|
  attn_fused<<<1024, 256, 0, stream>>>(QQ, KQQ, VT, FBUF, M, M + 16);
  quant_f32_signed<<<2048, 256, 0, stream>>>(FBUF, CTXQ, M + 16, 1.0f, 1024 * 1024);

  // out-projection -> AOF (FBUF)
  gemm_i8<<<dim3(32, 8), 256, 0, stream>>>(CTXQ, WOQ, FBUF, nullptr, M + 16, 1.f, 127.f, M + 7, BIASO, nullptr, 0, 0, M + 17, 1024, 1024);

  // residual + layernorm -> X1F (arena1)
  ln_res<<<4096, 256, 0, stream>>>(XQ, M + 0, FBUF, M + 17, X1F, M + 18);
  quant_f32_signed<<<2048, 256, 0, stream>>>(X1F, X1Q, M + 18, 1.0f, 1024 * 1024);

  // MLP1 two-pass (no 64 MB hidden buffer): pass1 stats, pass2 store u8-128
  gemm_i8<<<dim3(32, 32), 256, 0, stream>>>(X1Q, W1Q, nullptr, nullptr, M + 18, 1.f, 127.f, M + 9, BIAS1, nullptr, 1, 1, M + 19, 1024, 4096);
  gemm_i8<<<dim3(32, 32), 256, 0, stream>>>(X1Q, W1Q, nullptr, HQ,      M + 18, 1.f, 127.f, M + 9, BIAS1, nullptr, 1, 2, M + 19, 1024, 4096);

  // MLP2 with u8 offset correction -> H2F (FBUF)
  gemm_i8<<<dim3(32, 8), 256, 0, stream>>>(HQ, W2Q, FBUF, nullptr, M + 19, 1.f, 255.f, M + 11, BIAS2, RS, 0, 0, M + 20, 4096, 1024);

  // final residual + layernorm -> f32 out
  ln_final<<<4096, 256, 0, stream>>>(X1Q, M + 18, FBUF, M + 20, (float*)d_out);
}

// Round 5
// 554.392 us; speedup vs baseline: 1.5780x; 1.5780x over previous
//
#include <hip/hip_runtime.h>
#include <stdint.h>
#include <stddef.h>

// ---------------------------------------------------------------------------
// Fully fake-quantized transformer block on MI355X (gfx950).
// All GEMMs run as int8 MFMA (v_mfma_i32_16x16x64_i8), exact i32 accumulation,
// dequant in f32 epilogues. Attention fused flash-style.
// R4->R5: stat atomics de-contended. R4 rocprof: ln_res 190.9us with 16384
// same-address atomicMax = 11.3 ns/atomic serialized at L2. Now: block-level
// LDS reduce -> 1 atomic/block scattered over 64 slots; consumers fold 64.
// Workspace peak: 52.07 MB.
// ---------------------------------------------------------------------------

typedef unsigned short u16;
typedef __attribute__((ext_vector_type(4))) int   i32x4;
typedef __attribute__((ext_vector_type(4))) float f32x4;

#define DEV __device__ __forceinline__

DEV float bf2f(u16 u) { return __uint_as_float(((unsigned)u) << 16); }
DEV void atomicMaxF(float* p, float v) { atomicMax((unsigned*)p, __float_as_uint(v)); }
DEV float waveMax(float v) {
#pragma unroll
  for (int o = 32; o; o >>= 1) v = fmaxf(v, __shfl_xor(v, o, 64));
  return v;
}
DEV float waveSum(float v) {
#pragma unroll
  for (int o = 32; o; o >>= 1) v += __shfl_xor(v, o, 64);
  return v;
}
DEV int waveSumI(int v) {
#pragma unroll
  for (int o = 32; o; o >>= 1) v += __shfl_xor(v, o, 64);
  return v;
}
// block-wide max -> ONE atomic per block, scattered over 64 slots (G12)
DEV void blockStatMax(float v, float* __restrict__ slot64, float* sred4, int flatBlk) {
  v = waveMax(v);
  const int tid = threadIdx.x;
  if ((tid & 63) == 0) sred4[tid >> 6] = v;
  __syncthreads();
  if (tid == 0) {
    float m = fmaxf(fmaxf(sred4[0], sred4[1]), fmaxf(sred4[2], sred4[3]));
    atomicMaxF(&slot64[flatBlk & 63], m);
  }
}
// consumer-side fold of a 64-slot stat (uniform address -> scalar loads)
DEV float slotMax64(const float* __restrict__ s) {
  float m = 0.f;
#pragma unroll
  for (int i = 0; i < 64; ++i) m = fmaxf(m, s[i]);
  return m;
}
// load 4 consecutive input elements (group index i4) as f32, either dtype
DEV f32x4 ld4(const void* p, int i4, int isf32) {
  if (isf32) return ((const f32x4*)p)[i4];
  ushort4 u = ((const ushort4*)p)[i4];
  return (f32x4){bf2f(u.x), bf2f(u.y), bf2f(u.z), bf2f(u.w)};
}
// async global->LDS, 16B/lane; wave-uniform base + lane*16 (m97 pattern)
DEV void gll16(const void* g, void* l) {
  __builtin_amdgcn_global_load_lds((__attribute__((address_space(1))) void*)(g),
                                   (__attribute__((address_space(3))) void*)(l),
                                   16, 0, 0);
}

// --------------------------- input dtype probe -------------------------------
__global__ void detect_f32(const u16* __restrict__ x, int* __restrict__ flag) {
  const int tid = threadIdx.x;  // 64 threads
  int cnt = 0;
#pragma unroll
  for (int i = 0; i < 16; ++i) {
    u16 u = x[tid * 16 + i];
    if ((u & 0x7f80u) >= 0x4380u) ++cnt;
  }
  cnt = waveSumI(cnt);
  if (tid == 0) flag[0] = (cnt > 16) ? 1 : 0;
}

// --------------------------- reductions over inputs -------------------------
struct AJobs { const void* p[13]; int n4[13]; int bstart[14]; };

__global__ __launch_bounds__(256) void absmax_multi(AJobs J, float* __restrict__ M,
                                                    const int* __restrict__ flagp) {
  __shared__ float sred[4];
  const int isf32 = flagp[0];
  const int blk = blockIdx.x, tid = threadIdx.x;
  int j = 0;
  while (j < 12 && blk >= J.bstart[j + 1]) ++j;
  const int lb = blk - J.bstart[j];
  const int nb = J.bstart[j + 1] - J.bstart[j];
  float mx = 0.f;
  const void* p = J.p[j];
  for (int i = lb * 256 + tid; i < J.n4[j]; i += nb * 256) {
    f32x4 v = ld4(p, i, isf32);
    mx = fmaxf(mx, fmaxf(fmaxf(fabsf(v.x), fabsf(v.y)),
                         fmaxf(fabsf(v.z), fabsf(v.w))));
  }
  blockStatMax(mx, M + j * 64, sred, lb);
}

// --------------------------- quantizers -------------------------------------
__global__ __launch_bounds__(256) void quant_in_signed(
    const void* __restrict__ in, int8_t* __restrict__ out,
    const float* __restrict__ mp, const int* __restrict__ flagp, int n4) {
  const int isf32 = flagp[0];
  const float s = fmaxf(slotMax64(mp), 1e-8f) / 127.0f;
  char4* op = (char4*)out;
  for (int i = blockIdx.x * 256 + threadIdx.x; i < n4; i += gridDim.x * 256) {
    f32x4 v = ld4(in, i, isf32);
    char4 q;
    q.x = (signed char)fminf(fmaxf(rintf(v.x / s), -128.f), 127.f);
    q.y = (signed char)fminf(fmaxf(rintf(v.y / s), -128.f), 127.f);
    q.z = (signed char)fminf(fmaxf(rintf(v.z / s), -128.f), 127.f);
    q.w = (signed char)fminf(fmaxf(rintf(v.w / s), -128.f), 127.f);
    op[i] = q;
  }
}

struct WJobs { const void* in[5]; int8_t* out[5]; int mslot[5]; int n4[5]; int bstart[6]; };

__global__ __launch_bounds__(256) void quant_w_multi(WJobs J, const float* __restrict__ M,
                                                     const int* __restrict__ flagp) {
  const int isf32 = flagp[0];
  const int blk = blockIdx.x, tid = threadIdx.x;
  int j = 0;
  while (j < 4 && blk >= J.bstart[j + 1]) ++j;
  const int lb = blk - J.bstart[j];
  const int nb = J.bstart[j + 1] - J.bstart[j];
  const float s = fmaxf(slotMax64(M + J.mslot[j] * 64), 1e-8f) / 127.0f;
  const void* p = J.in[j];
  char4* o = (char4*)J.out[j];
  for (int i = lb * 256 + tid; i < J.n4[j]; i += nb * 256) {
    f32x4 v = ld4(p, i, isf32);
    char4 q;
    q.x = (signed char)fminf(fmaxf(rintf(v.x / s), -127.f), 127.f);
    q.y = (signed char)fminf(fmaxf(rintf(v.y / s), -127.f), 127.f);
    q.z = (signed char)fminf(fmaxf(rintf(v.z / s), -127.f), 127.f);
    q.w = (signed char)fminf(fmaxf(rintf(v.w / s), -127.f), 127.f);
    o[i] = q;
  }
}

// W2 (1024 x 4096) narrow quant + per-row int sum (u8 offset trick)
__global__ __launch_bounds__(256) void quant_w2_rs(
    const void* __restrict__ w2, int8_t* __restrict__ out,
    const float* __restrict__ mp, const int* __restrict__ flagp,
    int* __restrict__ rowsum) {
  const int isf32 = flagp[0];
  const int row = blockIdx.x, tid = threadIdx.x;
  const float s = fmaxf(slotMax64(mp), 1e-8f) / 127.0f;
  char4* op = (char4*)(out + (size_t)row * 4096);
  int sum = 0;
  for (int i = tid; i < 1024; i += 256) {
    f32x4 v = ld4(w2, row * 1024 + i, isf32);
    char4 q;
    q.x = (signed char)fminf(fmaxf(rintf(v.x / s), -127.f), 127.f);
    q.y = (signed char)fminf(fmaxf(rintf(v.y / s), -127.f), 127.f);
    q.z = (signed char)fminf(fmaxf(rintf(v.z / s), -127.f), 127.f);
    q.w = (signed char)fminf(fmaxf(rintf(v.w / s), -127.f), 127.f);
    op[i] = q;
    sum += (int)q.x + (int)q.y + (int)q.z + (int)q.w;
  }
  sum = waveSumI(sum);
  __shared__ int rs4[4];
  if ((tid & 63) == 0) rs4[tid >> 6] = sum;
  __syncthreads();
  if (tid == 0) rowsum[row] = rs4[0] + rs4[1] + rs4[2] + rs4[3];
}

struct BJobs { const void* in[6]; float* out[6]; int mslot[6]; int n4[6]; };

__global__ __launch_bounds__(256) void fq_bias_multi(BJobs J, const float* __restrict__ M,
                                                     const int* __restrict__ flagp) {
  const int isf32 = flagp[0];
  const int j = blockIdx.x;
  const float s = fmaxf(slotMax64(M + J.mslot[j] * 64), 1e-8f) / 127.0f;
  float* o = J.out[j];
  for (int i = threadIdx.x; i < J.n4[j]; i += 256) {
    f32x4 v = ld4(J.in[j], i, isf32);
    f32x4 r;
    r.x = fminf(fmaxf(rintf(v.x / s), -128.f), 127.f) * s;
    r.y = fminf(fmaxf(rintf(v.y / s), -128.f), 127.f) * s;
    r.z = fminf(fmaxf(rintf(v.z / s), -128.f), 127.f) * s;
    r.w = fminf(fmaxf(rintf(v.w / s), -128.f), 127.f) * s;
    *(f32x4*)(o + i * 4) = r;
  }
}

// f32 -> i8 signed (pre scales both value and stat; pre=0.125 for Q/sqrt(D))
__global__ __launch_bounds__(256) void quant_f32_signed(
    const float* __restrict__ in, int8_t* __restrict__ out,
    const float* __restrict__ mp, float pre, int n4) {
  const float s = fmaxf(slotMax64(mp) * pre, 1e-8f) / 127.0f;
  const f32x4* ip = (const f32x4*)in;
  char4* op = (char4*)out;
  for (int i = blockIdx.x * 256 + threadIdx.x; i < n4; i += gridDim.x * 256) {
    f32x4 v = ip[i];
    char4 q;
    q.x = (signed char)fminf(fmaxf(rintf(v.x * pre / s), -128.f), 127.f);
    q.y = (signed char)fminf(fmaxf(rintf(v.y * pre / s), -128.f), 127.f);
    q.z = (signed char)fminf(fmaxf(rintf(v.z * pre / s), -128.f), 127.f);
    q.w = (signed char)fminf(fmaxf(rintf(v.w * pre / s), -128.f), 127.f);
    op[i] = q;
  }
}

// V (f32 [b,s,h,d]) -> i8 transposed [b,h,d,s] so PV B-frags are k-contiguous
__global__ __launch_bounds__(256) void quant_v_t(
    const float* __restrict__ V, int8_t* __restrict__ Vt,
    const float* __restrict__ mp) {
  __shared__ float tile[64][65];
  const int bh = blockIdx.x, st = blockIdx.y;
  const int b = bh >> 4, h = bh & 15;
  const int tid = threadIdx.x;
  const float s = fmaxf(slotMax64(mp), 1e-8f) / 127.0f;
  const int r = tid >> 2, c = (tid & 3) * 16;
  const float* src = V + ((size_t)(b * 1024 + st * 64 + r)) * 1024 + h * 64 + c;
#pragma unroll
  for (int g = 0; g < 4; ++g) {
    f32x4 v = *(const f32x4*)(src + g * 4);
    tile[r][c + g * 4 + 0] = v.x;
    tile[r][c + g * 4 + 1] = v.y;
    tile[r][c + g * 4 + 2] = v.z;
    tile[r][c + g * 4 + 3] = v.w;
  }
  __syncthreads();
  unsigned wds[4];
#pragma unroll
  for (int g = 0; g < 4; ++g) {
    unsigned wd = 0;
#pragma unroll
    for (int k = 0; k < 4; ++k) {
      float v = tile[c + g * 4 + k][r];
      int q = (int)fminf(fmaxf(rintf(v / s), -128.f), 127.f);
      wd |= ((unsigned)(unsigned char)(signed char)q) << (8 * k);
    }
    wds[g] = wd;
  }
  i32x4 ov = {(int)wds[0], (int)wds[1], (int)wds[2], (int)wds[3]};
  *(i32x4*)(Vt + ((size_t)((b * 16 + h) * 64 + r)) * 1024 + st * 64 + c) = ov;
}

// --------------------------- int8 GEMM (m97-style) ---------------------------
// mode 0: store f32 Cf, stat->mOut ; mode 1: stats only ; mode 2: read stat,
// store clip(round(v/s),0,255)-128 as i8 Cq
__global__ __launch_bounds__(256) void gemm_i8(
    const int8_t* __restrict__ A, const int8_t* __restrict__ B,
    float* __restrict__ Cf, int8_t* __restrict__ Cq,
    const float* __restrict__ mA, float preA, float qmaxA,
    const float* __restrict__ mB,
    const float* __restrict__ bias, const int* __restrict__ extra,
    int relu, int mode, float* __restrict__ mOut, int K, int O) {
  __shared__ __align__(16) int8_t At[8192];
  __shared__ __align__(16) int8_t Bt[8192];
  __shared__ float sred[4];
  const int tid = threadIdx.x;
  const int nb = blockIdx.x, ob = blockIdx.y;
  const int w = tid >> 6, lane = tid & 63, l15 = lane & 15, quad = lane >> 4;
  const int wr = w >> 1, wc = w & 1;
  i32x4 acc[4][4];
#pragma unroll
  for (int i = 0; i < 4; ++i)
#pragma unroll
    for (int j = 0; j < 4; ++j) acc[i][j] = (i32x4){0, 0, 0, 0};
  const int r0 = tid >> 2, c0 = (tid & 3) * 16;
  const int8_t* Ab = A + (size_t)(nb * 128) * K;
  const int8_t* Bb = B + (size_t)(ob * 128) * K;
  for (int kt = 0; kt < K; kt += 64) {
    gll16(Ab + (size_t)r0 * K + kt + c0, At + tid * 16);
    gll16(Ab + (size_t)(r0 + 64) * K + kt + c0, At + 4096 + tid * 16);
    gll16(Bb + (size_t)r0 * K + kt + c0, Bt + tid * 16);
    gll16(Bb + (size_t)(r0 + 64) * K + kt + c0, Bt + 4096 + tid * 16);
    __syncthreads();
    i32x4 af[4], bf[4];
#pragma unroll
    for (int mt = 0; mt < 4; ++mt)
      af[mt] = *(const i32x4*)(At + (wr * 64 + mt * 16 + l15) * 64 + quad * 16);
#pragma unroll
    for (int nt = 0; nt < 4; ++nt)
      bf[nt] = *(const i32x4*)(Bt + (wc * 64 + nt * 16 + l15) * 64 + quad * 16);
#pragma unroll
    for (int mt = 0; mt < 4; ++mt)
#pragma unroll
      for (int nt = 0; nt < 4; ++nt)
        acc[mt][nt] = __builtin_amdgcn_mfma_i32_16x16x64_i8(af[mt], bf[nt], acc[mt][nt], 0, 0, 0);
    __syncthreads();
  }
  const float sA = fmaxf(slotMax64(mA) * preA, 1e-8f) / qmaxA;
  const float sB = fmaxf(slotMax64(mB), 1e-8f) / 127.0f;
  const float sAB = sA * sB;
  const float sq = (mode == 2) ? (fmaxf(slotMax64(mOut), 1e-8f) / 255.0f) : 1.0f;
  float lmax = 0.f;
#pragma unroll
  for (int mt = 0; mt < 4; ++mt) {
    const int n = nb * 128 + wr * 64 + mt * 16 + quad * 4;
#pragma unroll
    for (int nt = 0; nt < 4; ++nt) {
      const int o = ob * 128 + wc * 64 + nt * 16 + l15;
      const int ext = extra ? 128 * extra[o] : 0;
      const float bv = bias[o];
#pragma unroll
      for (int r = 0; r < 4; ++r) {
        float v = sAB * (float)(acc[mt][nt][r] + ext) + bv;
        if (relu) v = fmaxf(v, 0.f);
        if (mode == 0) Cf[(size_t)(n + r) * O + o] = v;
        else if (mode == 2) {
          int q = (int)fminf(fmaxf(rintf(v / sq), 0.f), 255.f) - 128;
          Cq[(size_t)(n + r) * O + o] = (int8_t)q;
        }
        lmax = fmaxf(lmax, fabsf(v));
      }
    }
  }
  if (mode != 2)
    blockStatMax(lmax, mOut, sred, nb + ob * gridDim.x);
}

// --------------------------- fused causal attention --------------------------
__global__ __launch_bounds__(256) void attn_fused(
    const int8_t* __restrict__ Qq, const int8_t* __restrict__ Kq,
    const int8_t* __restrict__ Vt, float* __restrict__ ctx,
    const float* __restrict__ M, float* __restrict__ mOut) {
  __shared__ __align__(16) int8_t qtile[4096];
  __shared__ __align__(16) int8_t ktile[4096];
  __shared__ __align__(16) int8_t vtile[4096];
  __shared__ __align__(16) float ptile[4096];
  __shared__ float sred[4];
  const int tid = threadIdx.x, bid = blockIdx.x;
  const int qt = bid & 15, h = (bid >> 4) & 15, b = bid >> 8;
  const int w = tid >> 6, lane = tid & 63, l15 = lane & 15, quad = lane >> 4;
  const float sqs = fmaxf(slotMax64(M + 13 * 64) * 0.125f, 1e-8f) / 127.0f;
  const float sk = fmaxf(slotMax64(M + 14 * 64), 1e-8f) / 127.0f;
  const float sv = fmaxf(slotMax64(M + 15 * 64), 1e-8f) / 127.0f;
  const float sqk = sqs * sk;
  const float s_attn = 1.0f / 127.0f;  // softmax global max is exactly 1.0
  const int r0 = tid >> 2, c0 = (tid & 3) * 16;

  gll16(Qq + ((size_t)(b * 1024 + qt * 64 + r0)) * 1024 + h * 64 + c0, qtile + tid * 16);
  __syncthreads();
  const i32x4 aq = *(const i32x4*)(qtile + (w * 16 + l15) * 64 + quad * 16);
  const int qrow0 = qt * 64 + w * 16 + quad * 4;

  float mrow[4] = {-1e30f, -1e30f, -1e30f, -1e30f};
  float lrow[4] = {0.f, 0.f, 0.f, 0.f};

  for (int kt = 0; kt <= qt; ++kt) {
    __syncthreads();
    gll16(Kq + ((size_t)(b * 1024 + kt * 64 + r0)) * 1024 + h * 64 + c0, ktile + tid * 16);
    __syncthreads();
    float sc[4][4];
#pragma unroll
    for (int nt = 0; nt < 4; ++nt) {
      i32x4 z = {0, 0, 0, 0};
      i32x4 bk = *(const i32x4*)(ktile + (nt * 16 + l15) * 64 + quad * 16);
      i32x4 d = __builtin_amdgcn_mfma_i32_16x16x64_i8(aq, bk, z, 0, 0, 0);
      const int kcol = kt * 64 + nt * 16 + l15;
#pragma unroll
      for (int r = 0; r < 4; ++r)
        sc[nt][r] = (kcol <= qrow0 + r) ? sqk * (float)d[r] : -1e30f;
    }
#pragma unroll
    for (int r = 0; r < 4; ++r) {
      float v = fmaxf(fmaxf(sc[0][r], sc[1][r]), fmaxf(sc[2][r], sc[3][r]));
      v = fmaxf(v, __shfl_xor(v, 1, 64));
      v = fmaxf(v, __shfl_xor(v, 2, 64));
      v = fmaxf(v, __shfl_xor(v, 4, 64));
      v = fmaxf(v, __shfl_xor(v, 8, 64));
      const float mn = fmaxf(mrow[r], v);
      float ps = expf(sc[0][r] - mn) + expf(sc[1][r] - mn) +
                 expf(sc[2][r] - mn) + expf(sc[3][r] - mn);
      ps += __shfl_xor(ps, 1, 64);
      ps += __shfl_xor(ps, 2, 64);
      ps += __shfl_xor(ps, 4, 64);
      ps += __shfl_xor(ps, 8, 64);
      lrow[r] = lrow[r] * expf(mrow[r] - mn) + ps;
      mrow[r] = mn;
    }
  }

  i32x4 cacc[4] = {{0, 0, 0, 0}, {0, 0, 0, 0}, {0, 0, 0, 0}, {0, 0, 0, 0}};
  for (int kt = 0; kt <= qt; ++kt) {
    __syncthreads();
    gll16(Kq + ((size_t)(b * 1024 + kt * 64 + r0)) * 1024 + h * 64 + c0, ktile + tid * 16);
    gll16(Vt + ((size_t)((b * 16 + h) * 64 + r0)) * 1024 + kt * 64 + c0, vtile + tid * 16);
    __syncthreads();
#pragma unroll
    for (int nt = 0; nt < 4; ++nt) {
      i32x4 z = {0, 0, 0, 0};
      i32x4 bk = *(const i32x4*)(ktile + (nt * 16 + l15) * 64 + quad * 16);
      i32x4 d = __builtin_amdgcn_mfma_i32_16x16x64_i8(aq, bk, z, 0, 0, 0);
      const int kcol = kt * 64 + nt * 16 + l15;
#pragma unroll
      for (int r = 0; r < 4; ++r) {
        float e = 0.f;
        if (kcol <= qrow0 + r)
          e = expf(sqk * (float)d[r] - mrow[r]) / lrow[r];
        ptile[(w * 16 + quad * 4 + r) * 64 + nt * 16 + l15] = e;
      }
    }
    __syncthreads();
    const float* pr = ptile + (w * 16 + l15) * 64 + quad * 16;
    unsigned pb[4];
#pragma unroll
    for (int g = 0; g < 4; ++g) {
      f32x4 pv = *(const f32x4*)(pr + g * 4);
      unsigned b0 = (unsigned)(int)fminf(fmaxf(rintf(pv.x * 127.0f), 0.f), 127.f);
      unsigned b1 = (unsigned)(int)fminf(fmaxf(rintf(pv.y * 127.0f), 0.f), 127.f);
      unsigned b2 = (unsigned)(int)fminf(fmaxf(rintf(pv.z * 127.0f), 0.f), 127.f);
      unsigned b3 = (unsigned)(int)fminf(fmaxf(rintf(pv.w * 127.0f), 0.f), 127.f);
      pb[g] = b0 | (b1 << 8) | (b2 << 16) | (b3 << 24);
    }
    i32x4 pf = {(int)pb[0], (int)pb[1], (int)pb[2], (int)pb[3]};
#pragma unroll
    for (int nt = 0; nt < 4; ++nt) {
      i32x4 bv = *(const i32x4*)(vtile + (nt * 16 + l15) * 64 + quad * 16);
      cacc[nt] = __builtin_amdgcn_mfma_i32_16x16x64_i8(pf, bv, cacc[nt], 0, 0, 0);
    }
  }
  const float sc2 = s_attn * sv;
  float lmax = 0.f;
#pragma unroll
  for (int nt = 0; nt < 4; ++nt) {
    const int d = nt * 16 + l15;
#pragma unroll
    for (int r = 0; r < 4; ++r) {
      float v = sc2 * (float)cacc[nt][r];
      ctx[((size_t)(b * 1024 + qrow0 + r)) * 1024 + h * 64 + d] = v;
      lmax = fmaxf(lmax, fabsf(v));
    }
  }
  blockStatMax(lmax, mOut, sred, bid);
}

// --------------------------- residual + layernorm ---------------------------
__global__ __launch_bounds__(256) void ln_res(
    const int8_t* __restrict__ xq, const float* __restrict__ mx,
    const float* __restrict__ ao, const float* __restrict__ ma,
    float* __restrict__ x1, float* __restrict__ mOut) {
  __shared__ float red[8];
  __shared__ float sred[4];
  const int row = blockIdx.x, tid = threadIdx.x;
  const float sx = fmaxf(slotMax64(mx), 1e-8f) / 127.0f;
  const float sa = fmaxf(slotMax64(ma), 1e-8f) / 127.0f;
  char4 xv = *(const char4*)(xq + (size_t)row * 1024 + tid * 4);
  f32x4 av = *(const f32x4*)(ao + (size_t)row * 1024 + tid * 4);
  float t[4];
  t[0] = (float)xv.x * sx + fminf(fmaxf(rintf(av.x / sa), -128.f), 127.f) * sa;
  t[1] = (float)xv.y * sx + fminf(fmaxf(rintf(av.y / sa), -128.f), 127.f) * sa;
  t[2] = (float)xv.z * sx + fminf(fmaxf(rintf(av.z / sa), -128.f), 127.f) * sa;
  t[3] = (float)xv.w * sx + fminf(fmaxf(rintf(av.w / sa), -128.f), 127.f) * sa;
  float s = waveSum(t[0] + t[1] + t[2] + t[3]);
  if ((tid & 63) == 0) red[tid >> 6] = s;
  __syncthreads();
  const float mean = (red[0] + red[1] + red[2] + red[3]) * (1.0f / 1024.0f);
  float vs = 0.f;
#pragma unroll
  for (int i = 0; i < 4; ++i) { float d = t[i] - mean; vs += d * d; }
  vs = waveSum(vs);
  if ((tid & 63) == 0) red[4 + (tid >> 6)] = vs;
  __syncthreads();
  const float var = (red[4] + red[5] + red[6] + red[7]) * (1.0f / 1024.0f);
  const float rs = sqrtf(var + 1e-5f);
  f32x4 o;
  o.x = (t[0] - mean) / rs;
  o.y = (t[1] - mean) / rs;
  o.z = (t[2] - mean) / rs;
  o.w = (t[3] - mean) / rs;
  *(f32x4*)(x1 + (size_t)row * 1024 + tid * 4) = o;
  float lmax = fmaxf(fmaxf(fabsf(o.x), fabsf(o.y)), fmaxf(fabsf(o.z), fabsf(o.w)));
  blockStatMax(lmax, mOut, sred, row);
}

// final residual + layernorm; OUTPUT IS FLOAT32 (reference returns f32)
__global__ __launch_bounds__(256) void ln_final(
    const int8_t* __restrict__ x1q, const float* __restrict__ mx1,
    const float* __restrict__ h2, const float* __restrict__ mh2,
    float* __restrict__ out) {
  __shared__ float red[8];
  const int row = blockIdx.x, tid = threadIdx.x;
  const float s1 = fmaxf(slotMax64(mx1), 1e-8f) / 127.0f;
  const float s2 = fmaxf(slotMax64(mh2), 1e-8f) / 127.0f;
  char4 xv = *(const char4*)(x1q + (size_t)row * 1024 + tid * 4);
  f32x4 hv = *(const f32x4*)(h2 + (size_t)row * 1024 + tid * 4);
  float t[4];
  t[0] = (float)xv.x * s1 + fminf(fmaxf(rintf(hv.x / s2), -128.f), 127.f) * s2;
  t[1] = (float)xv.y * s1 + fminf(fmaxf(rintf(hv.y / s2), -128.f), 127.f) * s2;
  t[2] = (float)xv.z * s1 + fminf(fmaxf(rintf(hv.z / s2), -128.f), 127.f) * s2;
  t[3] = (float)xv.w * s1 + fminf(fmaxf(rintf(hv.w / s2), -128.f), 127.f) * s2;
  float s = waveSum(t[0] + t[1] + t[2] + t[3]);
  if ((tid & 63) == 0) red[tid >> 6] = s;
  __syncthreads();
  const float mean = (red[0] + red[1] + red[2] + red[3]) * (1.0f / 1024.0f);
  float vs = 0.f;
#pragma unroll
  for (int i = 0; i < 4; ++i) { float d = t[i] - mean; vs += d * d; }
  vs = waveSum(vs);
  if ((tid & 63) == 0) red[4 + (tid >> 6)] = vs;
  __syncthreads();
  const float var = (red[4] + red[5] + red[6] + red[7]) * (1.0f / 1024.0f);
  const float rs = sqrtf(var + 1e-5f);
  f32x4 o;
  o.x = (t[0] - mean) / rs;
  o.y = (t[1] - mean) / rs;
  o.z = (t[2] - mean) / rs;
  o.w = (t[3] - mean) / rs;
  *(f32x4*)(out + (size_t)row * 1024 + tid * 4) = o;
}

// --------------------------- workspace layout (52.07 MB peak) ----------------
static constexpr size_t MB = 1u << 20;
static constexpr size_t OFF_M     = 0;        // 21 stats x 64 f32 slots = 5376 B
static constexpr size_t OFF_FLAG  = 5632;
static constexpr size_t OFF_BIASQ = 8192;
static constexpr size_t OFF_BIASK = OFF_BIASQ + 4096;
static constexpr size_t OFF_BIASV = OFF_BIASK + 4096;
static constexpr size_t OFF_BIASO = OFF_BIASV + 4096;
static constexpr size_t OFF_BIAS1 = OFF_BIASO + 4096;     // 4096 f32
static constexpr size_t OFF_BIAS2 = OFF_BIAS1 + 16384;
static constexpr size_t OFF_RS    = OFF_BIAS2 + 4096;     // 1024 i32
static constexpr size_t OFF_XQ    = 65536;                // 4 MB
static constexpr size_t OFF_WQQ   = OFF_XQ  + 4 * MB;     // 1 MB
static constexpr size_t OFF_WKQ   = OFF_WQQ + 1 * MB;
static constexpr size_t OFF_WVQ   = OFF_WKQ + 1 * MB;
static constexpr size_t OFF_WOQ   = OFF_WVQ + 1 * MB;
static constexpr size_t OFF_W1Q   = OFF_WOQ + 1 * MB;     // 4 MB
static constexpr size_t OFF_W2Q   = OFF_W1Q + 4 * MB;     // 4 MB
static constexpr size_t OFF_X1Q   = OFF_W2Q + 4 * MB;     // 4 MB
static constexpr size_t OFF_A1    = OFF_X1Q + 4 * MB;     // arena1, 16 MB
static constexpr size_t OFF_A2    = OFF_A1 + 16 * MB;     // arena2 (f32), 16 MB

extern "C" void kernel_launch(void* const* d_in, const int* in_sizes, int n_in,
                              void* d_out, int out_size, void* d_ws, size_t ws_size,
                              hipStream_t stream) {
  (void)n_in; (void)out_size; (void)ws_size;
  char* ws = (char*)d_ws;
  float* M = (float*)(ws + OFF_M);          // stat s lives at M + s*64, 64 slots
  int* FLAG = (int*)(ws + OFF_FLAG);
  float* BIASQ = (float*)(ws + OFF_BIASQ);
  float* BIASK = (float*)(ws + OFF_BIASK);
  float* BIASV = (float*)(ws + OFF_BIASV);
  float* BIASO = (float*)(ws + OFF_BIASO);
  float* BIAS1 = (float*)(ws + OFF_BIAS1);
  float* BIAS2 = (float*)(ws + OFF_BIAS2);
  int* RS = (int*)(ws + OFF_RS);
  int8_t* XQ  = (int8_t*)(ws + OFF_XQ);
  int8_t* WQQ = (int8_t*)(ws + OFF_WQQ);
  int8_t* WKQ = (int8_t*)(ws + OFF_WKQ);
  int8_t* WVQ = (int8_t*)(ws + OFF_WVQ);
  int8_t* WOQ = (int8_t*)(ws + OFF_WOQ);
  int8_t* W1Q = (int8_t*)(ws + OFF_W1Q);
  int8_t* W2Q = (int8_t*)(ws + OFF_W2Q);
  int8_t* X1Q = (int8_t*)(ws + OFF_X1Q);
  int8_t* QQ   = (int8_t*)(ws + OFF_A1);
  int8_t* KQQ  = (int8_t*)(ws + OFF_A1 + 4 * MB);
  int8_t* VT   = (int8_t*)(ws + OFF_A1 + 8 * MB);
  int8_t* CTXQ = (int8_t*)(ws + OFF_A1 + 12 * MB);
  float*  X1F  = (float*)(ws + OFF_A1);
  int8_t* HQ   = (int8_t*)(ws + OFF_A1);
  float* FBUF = (float*)(ws + OFF_A2);

  hipMemsetAsync(M, 0, 8192, stream);
  detect_f32<<<1, 64, 0, stream>>>((const u16*)d_in[0], FLAG);

  AJobs aj;
  const int ablk[13] = {512, 128, 1, 128, 1, 128, 1, 128, 1, 512, 2, 512, 1};
  int bs = 0;
  for (int i = 0; i < 13; ++i) {
    aj.p[i] = d_in[i];
    aj.n4[i] = in_sizes[i] / 4;
    aj.bstart[i] = bs;
    bs += ablk[i];
  }
  aj.bstart[13] = bs;
  absmax_multi<<<bs, 256, 0, stream>>>(aj, M, FLAG);

  quant_in_signed<<<1024, 256, 0, stream>>>(d_in[0], XQ, M + 0 * 64, FLAG, in_sizes[0] / 4);

  WJobs wj;
  const int widx[5] = {1, 3, 5, 7, 9};
  int8_t* wout[5] = {WQQ, WKQ, WVQ, WOQ, W1Q};
  const int wblk[5] = {128, 128, 128, 128, 512};
  int wb = 0;
  for (int j = 0; j < 5; ++j) {
    wj.in[j] = d_in[widx[j]];
    wj.out[j] = wout[j];
    wj.mslot[j] = widx[j];
    wj.n4[j] = in_sizes[widx[j]] / 4;
    wj.bstart[j] = wb;
    wb += wblk[j];
  }
  wj.bstart[5] = wb;
  quant_w_multi<<<wb, 256, 0, stream>>>(wj, M, FLAG);
  quant_w2_rs<<<1024, 256, 0, stream>>>(d_in[11], W2Q, M + 11 * 64, FLAG, RS);

  BJobs bj;
  const int bidx[6] = {2, 4, 6, 8, 10, 12};
  float* bout[6] = {BIASQ, BIASK, BIASV, BIASO, BIAS1, BIAS2};
  for (int j = 0; j < 6; ++j) {
    bj.in[j] = d_in[bidx[j]];
    bj.out[j] = bout[j];
    bj.mslot[j] = bidx[j];
    bj.n4[j] = in_sizes[bidx[j]] / 4;
  }
  fq_bias_multi<<<6, 256, 0, stream>>>(bj, M, FLAG);

  // Q proj -> FBUF -> QQ
  gemm_i8<<<dim3(32, 8), 256, 0, stream>>>(XQ, WQQ, FBUF, nullptr, M + 0 * 64, 1.f, 127.f, M + 1 * 64, BIASQ, nullptr, 0, 0, M + 13 * 64, 1024, 1024);
  quant_f32_signed<<<2048, 256, 0, stream>>>(FBUF, QQ, M + 13 * 64, 0.125f, 1024 * 1024);
  // K proj -> FBUF -> KQ
  gemm_i8<<<dim3(32, 8), 256, 0, stream>>>(XQ, WKQ, FBUF, nullptr, M + 0 * 64, 1.f, 127.f, M + 3 * 64, BIASK, nullptr, 0, 0, M + 14 * 64, 1024, 1024);
  quant_f32_signed<<<2048, 256, 0, stream>>>(FBUF, KQQ, M + 14 * 64, 1.0f, 1024 * 1024);
  // V proj -> FBUF -> VT ([b,h,d,s])
  gemm_i8<<<dim3(32, 8), 256, 0, stream>>>(XQ, WVQ, FBUF, nullptr, M + 0 * 64, 1.f, 127.f, M + 5 * 64, BIASV, nullptr, 0, 0, M + 15 * 64, 1024, 1024);
  quant_v_t<<<dim3(64, 16), 256, 0, stream>>>(FBUF, VT, M + 15 * 64);

  // fused causal attention -> ctx f32 (FBUF) + max|ctx|
  attn_fused<<<1024, 256, 0, stream>>>(QQ, KQQ, VT, FBUF, M, M + 16 * 64);
  quant_f32_signed<<<2048, 256, 0, stream>>>(FBUF, CTXQ, M + 16 * 64, 1.0f, 1024 * 1024);

  // out-projection -> AOF (FBUF)
  gemm_i8<<<dim3(32, 8), 256, 0, stream>>>(CTXQ, WOQ, FBUF, nullptr, M + 16 * 64, 1.f, 127.f, M + 7 * 64, BIASO, nullptr, 0, 0, M + 17 * 64, 1024, 1024);

  // residual + layernorm -> X1F (arena1)
  ln_res<<<4096, 256, 0, stream>>>(XQ, M + 0 * 64, FBUF, M + 17 * 64, X1F, M + 18 * 64);
  quant_f32_signed<<<2048, 256, 0, stream>>>(X1F, X1Q, M + 18 * 64, 1.0f, 1024 * 1024);

  // MLP1 two-pass: pass1 stats, pass2 store u8-128
  gemm_i8<<<dim3(32, 32), 256, 0, stream>>>(X1Q, W1Q, nullptr, nullptr, M + 18 * 64, 1.f, 127.f, M + 9 * 64, BIAS1, nullptr, 1, 1, M + 19 * 64, 1024, 4096);
  gemm_i8<<<dim3(32, 32), 256, 0, stream>>>(X1Q, W1Q, nullptr, HQ,      M + 18 * 64, 1.f, 127.f, M + 9 * 64, BIAS1, nullptr, 1, 2, M + 19 * 64, 1024, 4096);

  // MLP2 with u8 offset correction -> H2F (FBUF)
  gemm_i8<<<dim3(32, 8), 256, 0, stream>>>(HQ, W2Q, FBUF, nullptr, M + 19 * 64, 1.f, 255.f, M + 11 * 64, BIAS2, RS, 0, 0, M + 20 * 64, 4096, 1024);

  // final residual + layernorm -> f32 out
  ln_final<<<4096, 256, 0, stream>>>(X1Q, M + 18 * 64, FBUF, M + 20 * 64, (float*)d_out);
}

// Round 7
// 487.185 us; speedup vs baseline: 1.7957x; 1.1380x over previous
//
#include <hip/hip_runtime.h>
#include <stdint.h>
#include <stddef.h>

// ---------------------------------------------------------------------------
// Fully fake-quantized transformer block on MI355X (gfx950).
// i8 MFMA GEMMs (exact i32 acc), flash-style fused attention.
// R6->R7: FIX - R6's fused-QKV wrote 16MB slices at 4MB stride (overlap+OOB,
// absmax 0.496). Reverted to R5's three serial QKV GEMMs (known correct).
// KEPT from R6 (now isolated for test): attn rewrite (per-lane online softmax
// + single merge, dbuf K/V, ptile stride 68 -> no 16-way bank conflict,
// wave-private P transpose, longest-first qt, __expf) and gemm_i8 dbuf K-loop.
// ---------------------------------------------------------------------------

typedef unsigned short u16;
typedef __attribute__((ext_vector_type(4))) int   i32x4;
typedef __attribute__((ext_vector_type(4))) float f32x4;

#define DEV __device__ __forceinline__

DEV float bf2f(u16 u) { return __uint_as_float(((unsigned)u) << 16); }
DEV void atomicMaxF(float* p, float v) { atomicMax((unsigned*)p, __float_as_uint(v)); }
DEV float waveMax(float v) {
#pragma unroll
  for (int o = 32; o; o >>= 1) v = fmaxf(v, __shfl_xor(v, o, 64));
  return v;
}
DEV float waveSum(float v) {
#pragma unroll
  for (int o = 32; o; o >>= 1) v += __shfl_xor(v, o, 64);
  return v;
}
DEV int waveSumI(int v) {
#pragma unroll
  for (int o = 32; o; o >>= 1) v += __shfl_xor(v, o, 64);
  return v;
}
DEV void blockStatMax(float v, float* __restrict__ slot64, float* sred4, int flatBlk) {
  v = waveMax(v);
  const int tid = threadIdx.x;
  if ((tid & 63) == 0) sred4[tid >> 6] = v;
  __syncthreads();
  if (tid == 0) {
    float m = fmaxf(fmaxf(sred4[0], sred4[1]), fmaxf(sred4[2], sred4[3]));
    atomicMaxF(&slot64[flatBlk & 63], m);
  }
}
DEV float slotMax64(const float* __restrict__ s) {
  float m = 0.f;
#pragma unroll
  for (int i = 0; i < 64; ++i) m = fmaxf(m, s[i]);
  return m;
}
DEV f32x4 ld4(const void* p, int i4, int isf32) {
  if (isf32) return ((const f32x4*)p)[i4];
  ushort4 u = ((const ushort4*)p)[i4];
  return (f32x4){bf2f(u.x), bf2f(u.y), bf2f(u.z), bf2f(u.w)};
}
DEV void gll16(const void* g, void* l) {
  __builtin_amdgcn_global_load_lds((__attribute__((address_space(1))) void*)(g),
                                   (__attribute__((address_space(3))) void*)(l),
                                   16, 0, 0);
}

__global__ void detect_f32(const u16* __restrict__ x, int* __restrict__ flag) {
  const int tid = threadIdx.x;
  int cnt = 0;
#pragma unroll
  for (int i = 0; i < 16; ++i) {
    u16 u = x[tid * 16 + i];
    if ((u & 0x7f80u) >= 0x4380u) ++cnt;
  }
  cnt = waveSumI(cnt);
  if (tid == 0) flag[0] = (cnt > 16) ? 1 : 0;
}

struct AJobs { const void* p[13]; int n4[13]; int bstart[14]; };

__global__ __launch_bounds__(256) void absmax_multi(AJobs J, float* __restrict__ M,
                                                    const int* __restrict__ flagp) {
  __shared__ float sred[4];
  const int isf32 = flagp[0];
  const int blk = blockIdx.x, tid = threadIdx.x;
  int j = 0;
  while (j < 12 && blk >= J.bstart[j + 1]) ++j;
  const int lb = blk - J.bstart[j];
  const int nb = J.bstart[j + 1] - J.bstart[j];
  float mx = 0.f;
  const void* p = J.p[j];
  for (int i = lb * 256 + tid; i < J.n4[j]; i += nb * 256) {
    f32x4 v = ld4(p, i, isf32);
    mx = fmaxf(mx, fmaxf(fmaxf(fabsf(v.x), fabsf(v.y)),
                         fmaxf(fabsf(v.z), fabsf(v.w))));
  }
  blockStatMax(mx, M + j * 64, sred, lb);
}

__global__ __launch_bounds__(256) void quant_in_signed(
    const void* __restrict__ in, int8_t* __restrict__ out,
    const float* __restrict__ mp, const int* __restrict__ flagp, int n4) {
  const int isf32 = flagp[0];
  const float s = fmaxf(slotMax64(mp), 1e-8f) / 127.0f;
  char4* op = (char4*)out;
  for (int i = blockIdx.x * 256 + threadIdx.x; i < n4; i += gridDim.x * 256) {
    f32x4 v = ld4(in, i, isf32);
    char4 q;
    q.x = (signed char)fminf(fmaxf(rintf(v.x / s), -128.f), 127.f);
    q.y = (signed char)fminf(fmaxf(rintf(v.y / s), -128.f), 127.f);
    q.z = (signed char)fminf(fmaxf(rintf(v.z / s), -128.f), 127.f);
    q.w = (signed char)fminf(fmaxf(rintf(v.w / s), -128.f), 127.f);
    op[i] = q;
  }
}

struct WJobs { const void* in[5]; int8_t* out[5]; int mslot[5]; int n4[5]; int bstart[6]; };

__global__ __launch_bounds__(256) void quant_w_multi(WJobs J, const float* __restrict__ M,
                                                     const int* __restrict__ flagp) {
  const int isf32 = flagp[0];
  const int blk = blockIdx.x, tid = threadIdx.x;
  int j = 0;
  while (j < 4 && blk >= J.bstart[j + 1]) ++j;
  const int lb = blk - J.bstart[j];
  const int nb = J.bstart[j + 1] - J.bstart[j];
  const float s = fmaxf(slotMax64(M + J.mslot[j] * 64), 1e-8f) / 127.0f;
  const void* p = J.in[j];
  char4* o = (char4*)J.out[j];
  for (int i = lb * 256 + tid; i < J.n4[j]; i += nb * 256) {
    f32x4 v = ld4(p, i, isf32);
    char4 q;
    q.x = (signed char)fminf(fmaxf(rintf(v.x / s), -127.f), 127.f);
    q.y = (signed char)fminf(fmaxf(rintf(v.y / s), -127.f), 127.f);
    q.z = (signed char)fminf(fmaxf(rintf(v.z / s), -127.f), 127.f);
    q.w = (signed char)fminf(fmaxf(rintf(v.w / s), -127.f), 127.f);
    o[i] = q;
  }
}

__global__ __launch_bounds__(256) void quant_w2_rs(
    const void* __restrict__ w2, int8_t* __restrict__ out,
    const float* __restrict__ mp, const int* __restrict__ flagp,
    int* __restrict__ rowsum) {
  const int isf32 = flagp[0];
  const int row = blockIdx.x, tid = threadIdx.x;
  const float s = fmaxf(slotMax64(mp), 1e-8f) / 127.0f;
  char4* op = (char4*)(out + (size_t)row * 4096);
  int sum = 0;
  for (int i = tid; i < 1024; i += 256) {
    f32x4 v = ld4(w2, row * 1024 + i, isf32);
    char4 q;
    q.x = (signed char)fminf(fmaxf(rintf(v.x / s), -127.f), 127.f);
    q.y = (signed char)fminf(fmaxf(rintf(v.y / s), -127.f), 127.f);
    q.z = (signed char)fminf(fmaxf(rintf(v.z / s), -127.f), 127.f);
    q.w = (signed char)fminf(fmaxf(rintf(v.w / s), -127.f), 127.f);
    op[i] = q;
    sum += (int)q.x + (int)q.y + (int)q.z + (int)q.w;
  }
  sum = waveSumI(sum);
  __shared__ int rs4[4];
  if ((tid & 63) == 0) rs4[tid >> 6] = sum;
  __syncthreads();
  if (tid == 0) rowsum[row] = rs4[0] + rs4[1] + rs4[2] + rs4[3];
}

struct BJobs { const void* in[6]; float* out[6]; int mslot[6]; int n4[6]; };

__global__ __launch_bounds__(256) void fq_bias_multi(BJobs J, const float* __restrict__ M,
                                                     const int* __restrict__ flagp) {
  const int isf32 = flagp[0];
  const int j = blockIdx.x;
  const float s = fmaxf(slotMax64(M + J.mslot[j] * 64), 1e-8f) / 127.0f;
  float* o = J.out[j];
  for (int i = threadIdx.x; i < J.n4[j]; i += 256) {
    f32x4 v = ld4(J.in[j], i, isf32);
    f32x4 r;
    r.x = fminf(fmaxf(rintf(v.x / s), -128.f), 127.f) * s;
    r.y = fminf(fmaxf(rintf(v.y / s), -128.f), 127.f) * s;
    r.z = fminf(fmaxf(rintf(v.z / s), -128.f), 127.f) * s;
    r.w = fminf(fmaxf(rintf(v.w / s), -128.f), 127.f) * s;
    *(f32x4*)(o + i * 4) = r;
  }
}

__global__ __launch_bounds__(256) void quant_f32_signed(
    const float* __restrict__ in, int8_t* __restrict__ out,
    const float* __restrict__ mp, float pre, int n4) {
  const float s = fmaxf(slotMax64(mp) * pre, 1e-8f) / 127.0f;
  const f32x4* ip = (const f32x4*)in;
  char4* op = (char4*)out;
  for (int i = blockIdx.x * 256 + threadIdx.x; i < n4; i += gridDim.x * 256) {
    f32x4 v = ip[i];
    char4 q;
    q.x = (signed char)fminf(fmaxf(rintf(v.x * pre / s), -128.f), 127.f);
    q.y = (signed char)fminf(fmaxf(rintf(v.y * pre / s), -128.f), 127.f);
    q.z = (signed char)fminf(fmaxf(rintf(v.z * pre / s), -128.f), 127.f);
    q.w = (signed char)fminf(fmaxf(rintf(v.w * pre / s), -128.f), 127.f);
    op[i] = q;
  }
}

__global__ __launch_bounds__(256) void quant_v_t(
    const float* __restrict__ V, int8_t* __restrict__ Vt,
    const float* __restrict__ mp) {
  __shared__ float tile[64][65];
  const int bh = blockIdx.x, st = blockIdx.y;
  const int b = bh >> 4, h = bh & 15;
  const int tid = threadIdx.x;
  const float s = fmaxf(slotMax64(mp), 1e-8f) / 127.0f;
  const int r = tid >> 2, c = (tid & 3) * 16;
  const float* src = V + ((size_t)(b * 1024 + st * 64 + r)) * 1024 + h * 64 + c;
#pragma unroll
  for (int g = 0; g < 4; ++g) {
    f32x4 v = *(const f32x4*)(src + g * 4);
    tile[r][c + g * 4 + 0] = v.x;
    tile[r][c + g * 4 + 1] = v.y;
    tile[r][c + g * 4 + 2] = v.z;
    tile[r][c + g * 4 + 3] = v.w;
  }
  __syncthreads();
  unsigned wds[4];
#pragma unroll
  for (int g = 0; g < 4; ++g) {
    unsigned wd = 0;
#pragma unroll
    for (int k = 0; k < 4; ++k) {
      float v = tile[c + g * 4 + k][r];
      int q = (int)fminf(fmaxf(rintf(v / s), -128.f), 127.f);
      wd |= ((unsigned)(unsigned char)(signed char)q) << (8 * k);
    }
    wds[g] = wd;
  }
  i32x4 ov = {(int)wds[0], (int)wds[1], (int)wds[2], (int)wds[3]};
  *(i32x4*)(Vt + ((size_t)((b * 16 + h) * 64 + r)) * 1024 + st * 64 + c) = ov;
}

// --------------------------- int8 GEMM (dbuf K-loop) -------------------------
// mode 0: store f32 Cf, stat->mOut ; mode 1: stats only ; mode 2: requant u8-128
__global__ __launch_bounds__(256) void gemm_i8(
    const int8_t* __restrict__ A, const int8_t* __restrict__ B,
    float* __restrict__ Cf, int8_t* __restrict__ Cq,
    const float* __restrict__ mA, float preA, float qmaxA,
    const float* __restrict__ mB,
    const float* __restrict__ bias, const int* __restrict__ extra,
    int relu, int mode, float* __restrict__ mOut, int K, int O) {
  __shared__ __align__(16) int8_t At[2][8192];
  __shared__ __align__(16) int8_t Bt[2][8192];
  __shared__ float sred[4];
  const int tid = threadIdx.x;
  const int nb = blockIdx.x, ob = blockIdx.y;
  const int w = tid >> 6, lane = tid & 63, l15 = lane & 15, quad = lane >> 4;
  const int wr = w >> 1, wc = w & 1;
  i32x4 acc[4][4];
#pragma unroll
  for (int i = 0; i < 4; ++i)
#pragma unroll
    for (int j = 0; j < 4; ++j) acc[i][j] = (i32x4){0, 0, 0, 0};
  const int r0 = tid >> 2, c0 = (tid & 3) * 16;
  const int8_t* Ab = A + (size_t)(nb * 128) * K;
  const int8_t* Bb = B + (size_t)(ob * 128) * K;
  const int nk = K >> 6;
  gll16(Ab + (size_t)r0 * K + c0, At[0] + tid * 16);
  gll16(Ab + (size_t)(r0 + 64) * K + c0, At[0] + 4096 + tid * 16);
  gll16(Bb + (size_t)r0 * K + c0, Bt[0] + tid * 16);
  gll16(Bb + (size_t)(r0 + 64) * K + c0, Bt[0] + 4096 + tid * 16);
  for (int i = 0; i < nk; ++i) {
    __syncthreads();
    if (i + 1 < nk) {
      const int kt = (i + 1) << 6, b2 = (i + 1) & 1;
      gll16(Ab + (size_t)r0 * K + kt + c0, At[b2] + tid * 16);
      gll16(Ab + (size_t)(r0 + 64) * K + kt + c0, At[b2] + 4096 + tid * 16);
      gll16(Bb + (size_t)r0 * K + kt + c0, Bt[b2] + tid * 16);
      gll16(Bb + (size_t)(r0 + 64) * K + kt + c0, Bt[b2] + 4096 + tid * 16);
    }
    const int8_t* Ac = At[i & 1];
    const int8_t* Bc = Bt[i & 1];
    i32x4 af[4], bf[4];
#pragma unroll
    for (int mt = 0; mt < 4; ++mt)
      af[mt] = *(const i32x4*)(Ac + (wr * 64 + mt * 16 + l15) * 64 + quad * 16);
#pragma unroll
    for (int nt = 0; nt < 4; ++nt)
      bf[nt] = *(const i32x4*)(Bc + (wc * 64 + nt * 16 + l15) * 64 + quad * 16);
#pragma unroll
    for (int mt = 0; mt < 4; ++mt)
#pragma unroll
      for (int nt = 0; nt < 4; ++nt)
        acc[mt][nt] = __builtin_amdgcn_mfma_i32_16x16x64_i8(af[mt], bf[nt], acc[mt][nt], 0, 0, 0);
  }
  const float sA = fmaxf(slotMax64(mA) * preA, 1e-8f) / qmaxA;
  const float sB = fmaxf(slotMax64(mB), 1e-8f) / 127.0f;
  const float sAB = sA * sB;
  const float sq = (mode == 2) ? (fmaxf(slotMax64(mOut), 1e-8f) / 255.0f) : 1.0f;
  float lmax = 0.f;
#pragma unroll
  for (int mt = 0; mt < 4; ++mt) {
    const int n = nb * 128 + wr * 64 + mt * 16 + quad * 4;
#pragma unroll
    for (int nt = 0; nt < 4; ++nt) {
      const int o = ob * 128 + wc * 64 + nt * 16 + l15;
      const int ext = extra ? 128 * extra[o] : 0;
      const float bv = bias[o];
#pragma unroll
      for (int r = 0; r < 4; ++r) {
        float v = sAB * (float)(acc[mt][nt][r] + ext) + bv;
        if (relu) v = fmaxf(v, 0.f);
        if (mode == 0) Cf[(size_t)(n + r) * O + o] = v;
        else if (mode == 2) {
          int q = (int)fminf(fmaxf(rintf(v / sq), 0.f), 255.f) - 128;
          Cq[(size_t)(n + r) * O + o] = (int8_t)q;
        }
        lmax = fmaxf(lmax, fabsf(v));
      }
    }
  }
  if (mode != 2)
    blockStatMax(lmax, mOut, sred, nb + ob * gridDim.x);
}

// --------------------------- fused causal attention --------------------------
__global__ __launch_bounds__(256) void attn_fused(
    const int8_t* __restrict__ Qq, const int8_t* __restrict__ Kq,
    const int8_t* __restrict__ Vt, float* __restrict__ ctx,
    const float* __restrict__ M, float* __restrict__ mOut) {
  __shared__ __align__(16) int8_t qtile[4096];
  __shared__ __align__(16) int8_t ktile[2][4096];
  __shared__ __align__(16) int8_t vtile[2][4096];
  __shared__ __align__(16) float ptile[4 * 16 * 68];
  __shared__ float sred[4];
  const int tid = threadIdx.x, bid = blockIdx.x;
  const int qt = 15 - (bid & 15), h = (bid >> 4) & 15, b = bid >> 8;
  const int w = tid >> 6, lane = tid & 63, l15 = lane & 15, quad = lane >> 4;
  const float sqs = fmaxf(slotMax64(M + 13 * 64) * 0.125f, 1e-8f) / 127.0f;
  const float sk = fmaxf(slotMax64(M + 14 * 64), 1e-8f) / 127.0f;
  const float sv = fmaxf(slotMax64(M + 15 * 64), 1e-8f) / 127.0f;
  const float sqk = sqs * sk;
  const float s_attn = 1.0f / 127.0f;  // softmax global max == 1.0 exactly
  const int r0 = tid >> 2, c0 = (tid & 3) * 16;
  const int8_t* Kbase = Kq + (size_t)(b * 1024) * 1024 + h * 64 + c0;
  const int8_t* Vbase = Vt + (size_t)((b * 16 + h) * 64 + r0) * 1024 + c0;

  gll16(Qq + ((size_t)(b * 1024 + qt * 64 + r0)) * 1024 + h * 64 + c0, qtile + tid * 16);
  gll16(Kbase + (size_t)r0 * 1024, ktile[0] + tid * 16);
  __syncthreads();
  const i32x4 aq = *(const i32x4*)(qtile + (w * 16 + l15) * 64 + quad * 16);
  const int qrow0 = qt * 64 + w * 16 + quad * 4;

  // Phase A: per-lane online (m,l); single merge at the end
  float ml[4] = {-1e30f, -1e30f, -1e30f, -1e30f};
  float ll[4] = {0.f, 0.f, 0.f, 0.f};
  for (int kt = 0; kt <= qt; ++kt) {
    if (kt) __syncthreads();
    if (kt < qt)
      gll16(Kbase + (size_t)((kt + 1) * 64 + r0) * 1024, ktile[(kt + 1) & 1] + tid * 16);
    float sc[4][4];
#pragma unroll
    for (int nt = 0; nt < 4; ++nt) {
      i32x4 z = {0, 0, 0, 0};
      i32x4 bk = *(const i32x4*)(ktile[kt & 1] + (nt * 16 + l15) * 64 + quad * 16);
      i32x4 d = __builtin_amdgcn_mfma_i32_16x16x64_i8(aq, bk, z, 0, 0, 0);
      const int kcol = kt * 64 + nt * 16 + l15;
#pragma unroll
      for (int r = 0; r < 4; ++r)
        sc[nt][r] = (kcol <= qrow0 + r) ? sqk * (float)d[r] : -1e30f;
    }
#pragma unroll
    for (int r = 0; r < 4; ++r) {
      float vm = fmaxf(fmaxf(sc[0][r], sc[1][r]), fmaxf(sc[2][r], sc[3][r]));
      float mn = fmaxf(ml[r], vm);
      ll[r] = ll[r] * __expf(ml[r] - mn) +
              __expf(sc[0][r] - mn) + __expf(sc[1][r] - mn) +
              __expf(sc[2][r] - mn) + __expf(sc[3][r] - mn);
      ml[r] = mn;
    }
  }
  float rl[4];
#pragma unroll
  for (int r = 0; r < 4; ++r) {
#pragma unroll
    for (int off = 1; off <= 8; off <<= 1) {
      float om = __shfl_xor(ml[r], off, 64);
      float ol = __shfl_xor(ll[r], off, 64);
      float mn = fmaxf(ml[r], om);
      ll[r] = ll[r] * __expf(ml[r] - mn) + ol * __expf(om - mn);
      ml[r] = mn;
    }
    rl[r] = 1.0f / ll[r];
  }

  // Phase B: recompute scores, quantize P (wave-private transpose), PV in i32
  __syncthreads();
  gll16(Kbase + (size_t)r0 * 1024, ktile[0] + tid * 16);
  gll16(Vbase, vtile[0] + tid * 16);
  i32x4 cacc[4] = {{0, 0, 0, 0}, {0, 0, 0, 0}, {0, 0, 0, 0}, {0, 0, 0, 0}};
  float* pw = ptile + w * (16 * 68);
  for (int kt = 0; kt <= qt; ++kt) {
    __syncthreads();
    if (kt < qt) {
      gll16(Kbase + (size_t)((kt + 1) * 64 + r0) * 1024, ktile[(kt + 1) & 1] + tid * 16);
      gll16(Vbase + (kt + 1) * 64, vtile[(kt + 1) & 1] + tid * 16);
    }
#pragma unroll
    for (int nt = 0; nt < 4; ++nt) {
      i32x4 z = {0, 0, 0, 0};
      i32x4 bk = *(const i32x4*)(ktile[kt & 1] + (nt * 16 + l15) * 64 + quad * 16);
      i32x4 d = __builtin_amdgcn_mfma_i32_16x16x64_i8(aq, bk, z, 0, 0, 0);
      const int kcol = kt * 64 + nt * 16 + l15;
#pragma unroll
      for (int r = 0; r < 4; ++r) {
        float e = (kcol <= qrow0 + r) ? __expf(sqk * (float)d[r] - ml[r]) * rl[r] : 0.f;
        pw[(quad * 4 + r) * 68 + nt * 16 + l15] = e;
      }
    }
    const float* pr = pw + l15 * 68 + quad * 16;
    unsigned pb[4];
#pragma unroll
    for (int g = 0; g < 4; ++g) {
      f32x4 pv = *(const f32x4*)(pr + g * 4);
      unsigned b0 = (unsigned)(int)fminf(fmaxf(rintf(pv.x * 127.0f), 0.f), 127.f);
      unsigned b1 = (unsigned)(int)fminf(fmaxf(rintf(pv.y * 127.0f), 0.f), 127.f);
      unsigned b2 = (unsigned)(int)fminf(fmaxf(rintf(pv.z * 127.0f), 0.f), 127.f);
      unsigned b3 = (unsigned)(int)fminf(fmaxf(rintf(pv.w * 127.0f), 0.f), 127.f);
      pb[g] = b0 | (b1 << 8) | (b2 << 16) | (b3 << 24);
    }
    i32x4 pf = {(int)pb[0], (int)pb[1], (int)pb[2], (int)pb[3]};
#pragma unroll
    for (int nt = 0; nt < 4; ++nt) {
      i32x4 bv = *(const i32x4*)(vtile[kt & 1] + (nt * 16 + l15) * 64 + quad * 16);
      cacc[nt] = __builtin_amdgcn_mfma_i32_16x16x64_i8(pf, bv, cacc[nt], 0, 0, 0);
    }
  }
  const float sc2 = s_attn * sv;
  float lmax = 0.f;
#pragma unroll
  for (int nt = 0; nt < 4; ++nt) {
    const int d = nt * 16 + l15;
#pragma unroll
    for (int r = 0; r < 4; ++r) {
      float v = sc2 * (float)cacc[nt][r];
      ctx[((size_t)(b * 1024 + qrow0 + r)) * 1024 + h * 64 + d] = v;
      lmax = fmaxf(lmax, fabsf(v));
    }
  }
  blockStatMax(lmax, mOut, sred, bid);
}

// --------------------------- residual + layernorm ---------------------------
__global__ __launch_bounds__(256) void ln_res(
    const int8_t* __restrict__ xq, const float* __restrict__ mx,
    const float* __restrict__ ao, const float* __restrict__ ma,
    float* __restrict__ x1, float* __restrict__ mOut) {
  __shared__ float red[8];
  __shared__ float sred[4];
  const int row = blockIdx.x, tid = threadIdx.x;
  const float sx = fmaxf(slotMax64(mx), 1e-8f) / 127.0f;
  const float sa = fmaxf(slotMax64(ma), 1e-8f) / 127.0f;
  char4 xv = *(const char4*)(xq + (size_t)row * 1024 + tid * 4);
  f32x4 av = *(const f32x4*)(ao + (size_t)row * 1024 + tid * 4);
  float t[4];
  t[0] = (float)xv.x * sx + fminf(fmaxf(rintf(av.x / sa), -128.f), 127.f) * sa;
  t[1] = (float)xv.y * sx + fminf(fmaxf(rintf(av.y / sa), -128.f), 127.f) * sa;
  t[2] = (float)xv.z * sx + fminf(fmaxf(rintf(av.z / sa), -128.f), 127.f) * sa;
  t[3] = (float)xv.w * sx + fminf(fmaxf(rintf(av.w / sa), -128.f), 127.f) * sa;
  float s = waveSum(t[0] + t[1] + t[2] + t[3]);
  if ((tid & 63) == 0) red[tid >> 6] = s;
  __syncthreads();
  const float mean = (red[0] + red[1] + red[2] + red[3]) * (1.0f / 1024.0f);
  float vs = 0.f;
#pragma unroll
  for (int i = 0; i < 4; ++i) { float d = t[i] - mean; vs += d * d; }
  vs = waveSum(vs);
  if ((tid & 63) == 0) red[4 + (tid >> 6)] = vs;
  __syncthreads();
  const float var = (red[4] + red[5] + red[6] + red[7]) * (1.0f / 1024.0f);
  const float rs = sqrtf(var + 1e-5f);
  f32x4 o;
  o.x = (t[0] - mean) / rs;
  o.y = (t[1] - mean) / rs;
  o.z = (t[2] - mean) / rs;
  o.w = (t[3] - mean) / rs;
  *(f32x4*)(x1 + (size_t)row * 1024 + tid * 4) = o;
  float lmax = fmaxf(fmaxf(fabsf(o.x), fabsf(o.y)), fmaxf(fabsf(o.z), fabsf(o.w)));
  blockStatMax(lmax, mOut, sred, row);
}

__global__ __launch_bounds__(256) void ln_final(
    const int8_t* __restrict__ x1q, const float* __restrict__ mx1,
    const float* __restrict__ h2, const float* __restrict__ mh2,
    float* __restrict__ out) {
  __shared__ float red[8];
  const int row = blockIdx.x, tid = threadIdx.x;
  const float s1 = fmaxf(slotMax64(mx1), 1e-8f) / 127.0f;
  const float s2 = fmaxf(slotMax64(mh2), 1e-8f) / 127.0f;
  char4 xv = *(const char4*)(x1q + (size_t)row * 1024 + tid * 4);
  f32x4 hv = *(const f32x4*)(h2 + (size_t)row * 1024 + tid * 4);
  float t[4];
  t[0] = (float)xv.x * s1 + fminf(fmaxf(rintf(hv.x / s2), -128.f), 127.f) * s2;
  t[1] = (float)xv.y * s1 + fminf(fmaxf(rintf(hv.y / s2), -128.f), 127.f) * s2;
  t[2] = (float)xv.z * s1 + fminf(fmaxf(rintf(hv.z / s2), -128.f), 127.f) * s2;
  t[3] = (float)xv.w * s1 + fminf(fmaxf(rintf(hv.w / s2), -128.f), 127.f) * s2;
  float s = waveSum(t[0] + t[1] + t[2] + t[3]);
  if ((tid & 63) == 0) red[tid >> 6] = s;
  __syncthreads();
  const float mean = (red[0] + red[1] + red[2] + red[3]) * (1.0f / 1024.0f);
  float vs = 0.f;
#pragma unroll
  for (int i = 0; i < 4; ++i) { float d = t[i] - mean; vs += d * d; }
  vs = waveSum(vs);
  if ((tid & 63) == 0) red[4 + (tid >> 6)] = vs;
  __syncthreads();
  const float var = (red[4] + red[5] + red[6] + red[7]) * (1.0f / 1024.0f);
  const float rs = sqrtf(var + 1e-5f);
  f32x4 o;
  o.x = (t[0] - mean) / rs;
  o.y = (t[1] - mean) / rs;
  o.z = (t[2] - mean) / rs;
  o.w = (t[3] - mean) / rs;
  *(f32x4*)(out + (size_t)row * 1024 + tid * 4) = o;
}

// --------------------------- workspace layout (52.07 MB peak) ----------------
static constexpr size_t MB = 1u << 20;
static constexpr size_t OFF_M     = 0;          // 21 stats x 64 f32 slots
static constexpr size_t OFF_FLAG  = 6400;
static constexpr size_t OFF_BIASQ = 8192;
static constexpr size_t OFF_BIASK = OFF_BIASQ + 4096;
static constexpr size_t OFF_BIASV = OFF_BIASK + 4096;
static constexpr size_t OFF_BIASO = OFF_BIASV + 4096;
static constexpr size_t OFF_BIAS1 = OFF_BIASO + 4096;
static constexpr size_t OFF_BIAS2 = OFF_BIAS1 + 16384;
static constexpr size_t OFF_RS    = OFF_BIAS2 + 4096;
static constexpr size_t OFF_XQ    = 65536;
static constexpr size_t OFF_WQQ   = OFF_XQ  + 4 * MB;
static constexpr size_t OFF_WKQ   = OFF_WQQ + 1 * MB;
static constexpr size_t OFF_WVQ   = OFF_WKQ + 1 * MB;
static constexpr size_t OFF_WOQ   = OFF_WVQ + 1 * MB;
static constexpr size_t OFF_W1Q   = OFF_WOQ + 1 * MB;
static constexpr size_t OFF_W2Q   = OFF_W1Q + 4 * MB;
static constexpr size_t OFF_X1Q   = OFF_W2Q + 4 * MB;
static constexpr size_t OFF_A1    = OFF_X1Q + 4 * MB;     // arena1, 16 MB
static constexpr size_t OFF_A2    = OFF_A1 + 16 * MB;     // arena2 (f32), 16 MB

extern "C" void kernel_launch(void* const* d_in, const int* in_sizes, int n_in,
                              void* d_out, int out_size, void* d_ws, size_t ws_size,
                              hipStream_t stream) {
  (void)n_in; (void)out_size; (void)ws_size;
  char* ws = (char*)d_ws;
  float* M = (float*)(ws + OFF_M);
  int* FLAG = (int*)(ws + OFF_FLAG);
  float* BIASQ = (float*)(ws + OFF_BIASQ);
  float* BIASK = (float*)(ws + OFF_BIASK);
  float* BIASV = (float*)(ws + OFF_BIASV);
  float* BIASO = (float*)(ws + OFF_BIASO);
  float* BIAS1 = (float*)(ws + OFF_BIAS1);
  float* BIAS2 = (float*)(ws + OFF_BIAS2);
  int* RS = (int*)(ws + OFF_RS);
  int8_t* XQ  = (int8_t*)(ws + OFF_XQ);
  int8_t* WQQ = (int8_t*)(ws + OFF_WQQ);
  int8_t* WKQ = (int8_t*)(ws + OFF_WKQ);
  int8_t* WVQ = (int8_t*)(ws + OFF_WVQ);
  int8_t* WOQ = (int8_t*)(ws + OFF_WOQ);
  int8_t* W1Q = (int8_t*)(ws + OFF_W1Q);
  int8_t* W2Q = (int8_t*)(ws + OFF_W2Q);
  int8_t* X1Q = (int8_t*)(ws + OFF_X1Q);
  int8_t* QQ   = (int8_t*)(ws + OFF_A1);
  int8_t* KQQ  = (int8_t*)(ws + OFF_A1 + 4 * MB);
  int8_t* VT   = (int8_t*)(ws + OFF_A1 + 8 * MB);
  int8_t* CTXQ = (int8_t*)(ws + OFF_A1 + 12 * MB);
  float*  X1F  = (float*)(ws + OFF_A1);
  int8_t* HQ   = (int8_t*)(ws + OFF_A1);
  float* FBUF = (float*)(ws + OFF_A2);   // serial reuse: QF/KF/VF/ctx/ao/h2

  hipMemsetAsync(M, 0, 8192, stream);
  detect_f32<<<1, 64, 0, stream>>>((const u16*)d_in[0], FLAG);

  AJobs aj;
  const int ablk[13] = {512, 128, 1, 128, 1, 128, 1, 128, 1, 512, 2, 512, 1};
  int bs = 0;
  for (int i = 0; i < 13; ++i) {
    aj.p[i] = d_in[i];
    aj.n4[i] = in_sizes[i] / 4;
    aj.bstart[i] = bs;
    bs += ablk[i];
  }
  aj.bstart[13] = bs;
  absmax_multi<<<bs, 256, 0, stream>>>(aj, M, FLAG);

  quant_in_signed<<<1024, 256, 0, stream>>>(d_in[0], XQ, M + 0 * 64, FLAG, in_sizes[0] / 4);

  WJobs wj;
  const int widx[5] = {1, 3, 5, 7, 9};
  int8_t* wout[5] = {WQQ, WKQ, WVQ, WOQ, W1Q};
  const int wblk[5] = {128, 128, 128, 128, 512};
  int wb = 0;
  for (int j = 0; j < 5; ++j) {
    wj.in[j] = d_in[widx[j]];
    wj.out[j] = wout[j];
    wj.mslot[j] = widx[j];
    wj.n4[j] = in_sizes[widx[j]] / 4;
    wj.bstart[j] = wb;
    wb += wblk[j];
  }
  wj.bstart[5] = wb;
  quant_w_multi<<<wb, 256, 0, stream>>>(wj, M, FLAG);
  quant_w2_rs<<<1024, 256, 0, stream>>>(d_in[11], W2Q, M + 11 * 64, FLAG, RS);

  BJobs bj;
  const int bidx[6] = {2, 4, 6, 8, 10, 12};
  float* bout[6] = {BIASQ, BIASK, BIASV, BIASO, BIAS1, BIAS2};
  for (int j = 0; j < 6; ++j) {
    bj.in[j] = d_in[bidx[j]];
    bj.out[j] = bout[j];
    bj.mslot[j] = bidx[j];
    bj.n4[j] = in_sizes[bidx[j]] / 4;
  }
  fq_bias_multi<<<6, 256, 0, stream>>>(bj, M, FLAG);

  // Q/K/V projections through the 16MB f32 arena, strictly serial
  gemm_i8<<<dim3(32, 8), 256, 0, stream>>>(XQ, WQQ, FBUF, nullptr, M + 0 * 64, 1.f, 127.f, M + 1 * 64, BIASQ, nullptr, 0, 0, M + 13 * 64, 1024, 1024);
  quant_f32_signed<<<2048, 256, 0, stream>>>(FBUF, QQ, M + 13 * 64, 0.125f, 1024 * 1024);
  gemm_i8<<<dim3(32, 8), 256, 0, stream>>>(XQ, WKQ, FBUF, nullptr, M + 0 * 64, 1.f, 127.f, M + 3 * 64, BIASK, nullptr, 0, 0, M + 14 * 64, 1024, 1024);
  quant_f32_signed<<<2048, 256, 0, stream>>>(FBUF, KQQ, M + 14 * 64, 1.0f, 1024 * 1024);
  gemm_i8<<<dim3(32, 8), 256, 0, stream>>>(XQ, WVQ, FBUF, nullptr, M + 0 * 64, 1.f, 127.f, M + 5 * 64, BIASV, nullptr, 0, 0, M + 15 * 64, 1024, 1024);
  quant_v_t<<<dim3(64, 16), 256, 0, stream>>>(FBUF, VT, M + 15 * 64);

  attn_fused<<<1024, 256, 0, stream>>>(QQ, KQQ, VT, FBUF, M, M + 16 * 64);
  quant_f32_signed<<<2048, 256, 0, stream>>>(FBUF, CTXQ, M + 16 * 64, 1.0f, 1024 * 1024);

  gemm_i8<<<dim3(32, 8), 256, 0, stream>>>(CTXQ, WOQ, FBUF, nullptr, M + 16 * 64, 1.f, 127.f, M + 7 * 64, BIASO, nullptr, 0, 0, M + 17 * 64, 1024, 1024);

  ln_res<<<4096, 256, 0, stream>>>(XQ, M + 0 * 64, FBUF, M + 17 * 64, X1F, M + 18 * 64);
  quant_f32_signed<<<2048, 256, 0, stream>>>(X1F, X1Q, M + 18 * 64, 1.0f, 1024 * 1024);

  gemm_i8<<<dim3(32, 32), 256, 0, stream>>>(X1Q, W1Q, nullptr, nullptr, M + 18 * 64, 1.f, 127.f, M + 9 * 64, BIAS1, nullptr, 1, 1, M + 19 * 64, 1024, 4096);
  gemm_i8<<<dim3(32, 32), 256, 0, stream>>>(X1Q, W1Q, nullptr, HQ,      M + 18 * 64, 1.f, 127.f, M + 9 * 64, BIAS1, nullptr, 1, 2, M + 19 * 64, 1024, 4096);

  gemm_i8<<<dim3(32, 8), 256, 0, stream>>>(HQ, W2Q, FBUF, nullptr, M + 19 * 64, 1.f, 255.f, M + 11 * 64, BIAS2, RS, 0, 0, M + 20 * 64, 4096, 1024);

  ln_final<<<4096, 256, 0, stream>>>(X1Q, M + 18 * 64, FBUF, M + 20 * 64, (float*)d_out);
}